// Round 1
// baseline (5164.071 us; speedup 1.0000x reference)
//
#include <hip/hip_runtime.h>

#define DI __device__ __forceinline__

typedef __attribute__((ext_vector_type(8))) short short8;
typedef __attribute__((ext_vector_type(4))) float f32x4;
typedef unsigned short u16;

// ---------- helpers ----------
DI u16 f2bf(float f) {
    union { float f; unsigned u; } v; v.f = f;
    unsigned u = v.u;
    return (u16)((u + 0x7fffu + ((u >> 16) & 1u)) >> 16);   // RNE
}
DI float bf2f(u16 h) {
    union { unsigned u; float f; } v; v.u = ((unsigned)h) << 16;
    return v.f;
}
// byte offset of the 16B slot `slot` (0..3) of row `row` in a [rows][32]bf16
// tile, XOR-swizzled so 16-lane fragment reads are ~2-way conflict (free).
DI int lds_off(int row, int slot) {
    return row * 64 + (((slot ^ ((row >> 1) & 3)) << 4));
}

// ---------- generic MFMA GEMM: C[M,N] = A[M,K] @ B[K,N] (+bias,+resid,relu) ----------
// TM=64, TN=128, K-step 32. 256 threads = 4 waves (2x2), wave tile 32x64.
// AMODE: 0 = A f32; 1 = A f32 = A0+A1 (elementwise); 2 = A bf16 (u16)
// STORE: 0 = f32 linear ldc=N; 1 = bf16 "value layout" ((b*8+h)*8400+pix)*32+hd
template<int AMODE, int STORE, bool RELU, bool RESID>
__global__ __launch_bounds__(256) void k_gemm(
    const void* __restrict__ Ap, const float* __restrict__ A2,
    const float* __restrict__ Bw, const float* __restrict__ bias,
    const float* __restrict__ resid, void* __restrict__ Cp,
    int M, int N, int K)
{
    __shared__ alignas(16) char Asm[64 * 64];    // 64 rows x 32 bf16
    __shared__ alignas(16) char Bsm[128 * 64];   // 128 "rows"(=n) x 32 bf16 (B transposed)
    const int tid  = threadIdx.x;
    const int lane = tid & 63;
    const int wave = tid >> 6;
    const int wr = wave >> 1, wc = wave & 1;
    const int m0 = blockIdx.x * 64, n0 = blockIdx.y * 128;
    const bool fullN = (n0 + 128 <= N);

    f32x4 acc[2][4] = {};

    for (int kb = 0; kb < K; kb += 32) {
        // ---- stage A tile (64 x 32) ----
        if (AMODE == 2) {
            const u16* A = (const u16*)Ap;
            int r = tid >> 2, ko = (tid & 3) << 3;
            int grow = m0 + r; if (grow > M - 1) grow = M - 1;
            uint4 v = *(const uint4*)(A + (size_t)grow * K + kb + ko);
            *(uint4*)(Asm + lds_off(r, ko >> 3)) = v;
        } else {
            const float* A = (const float*)Ap;
#pragma unroll
            for (int j = 0; j < 2; j++) {
                int flat = tid + j * 256;           // 0..511
                int r = flat >> 3, kq = flat & 7;   // kq*4 = k offset
                int grow = m0 + r; if (grow > M - 1) grow = M - 1;
                const float* p = A + (size_t)grow * K + kb + (kq << 2);
                float4 v = *(const float4*)p;
                if (AMODE == 1) {
                    float4 w = *(const float4*)(A2 + (size_t)grow * K + kb + (kq << 2));
                    v.x += w.x; v.y += w.y; v.z += w.z; v.w += w.w;
                }
                ushort4 h; h.x = f2bf(v.x); h.y = f2bf(v.y); h.z = f2bf(v.z); h.w = f2bf(v.w);
                *(ushort4*)(Asm + lds_off(r, kq >> 1) + ((kq & 1) << 3)) = h;
            }
        }
        // ---- stage B tile (32 x 128) transposed into Bsm[n][k] ----
#pragma unroll
        for (int j = 0; j < 4; j++) {
            int flat = tid + j * 256;               // 0..1023
            int kk = flat >> 5, nq = (flat & 31) << 2;
            const float* brow = Bw + (size_t)(kb + kk) * N;
            float v0, v1, v2, v3;
            if (fullN) {
                float4 v = *(const float4*)(brow + n0 + nq);
                v0 = v.x; v1 = v.y; v2 = v.z; v3 = v.w;
            } else {
                int nm = N - 1;
                int a0 = n0 + nq, a1 = a0 + 1, a2 = a0 + 2, a3 = a0 + 3;
                v0 = brow[a0 > nm ? nm : a0]; v1 = brow[a1 > nm ? nm : a1];
                v2 = brow[a2 > nm ? nm : a2]; v3 = brow[a3 > nm ? nm : a3];
            }
            int slot = kk >> 3, kby = (kk & 7) << 1;
            *(u16*)(Bsm + lds_off(nq + 0, slot) + kby) = f2bf(v0);
            *(u16*)(Bsm + lds_off(nq + 1, slot) + kby) = f2bf(v1);
            *(u16*)(Bsm + lds_off(nq + 2, slot) + kby) = f2bf(v2);
            *(u16*)(Bsm + lds_off(nq + 3, slot) + kby) = f2bf(v3);
        }
        __syncthreads();

        short8 af[2], bfr[4];
#pragma unroll
        for (int mi = 0; mi < 2; mi++) {
            int r = (wr << 5) + (mi << 4) + (lane & 15);
            af[mi] = *(const short8*)(Asm + lds_off(r, lane >> 4));
        }
#pragma unroll
        for (int ni = 0; ni < 4; ni++) {
            int c = (wc << 6) + (ni << 4) + (lane & 15);
            bfr[ni] = *(const short8*)(Bsm + lds_off(c, lane >> 4));
        }
#pragma unroll
        for (int mi = 0; mi < 2; mi++)
#pragma unroll
            for (int ni = 0; ni < 4; ni++)
                acc[mi][ni] = __builtin_amdgcn_mfma_f32_16x16x32_bf16(af[mi], bfr[ni], acc[mi][ni], 0, 0, 0);
        __syncthreads();
    }

    // ---- epilogue: C/D layout col=lane&15, row=(lane>>4)*4+e ----
    const int cl = lane & 15, rb = (lane >> 4) << 2;
#pragma unroll
    for (int mi = 0; mi < 2; mi++) {
#pragma unroll
        for (int ni = 0; ni < 4; ni++) {
            int col = n0 + (wc << 6) + (ni << 4) + cl;
            if (col >= N) continue;
            float bv = bias[col];
#pragma unroll
            for (int e = 0; e < 4; e++) {
                int row = m0 + (wr << 5) + (mi << 4) + rb + e;
                if (row >= M) continue;
                float v = acc[mi][ni][e] + bv;
                if (RESID) v += resid[(size_t)row * N + col];
                if (RELU)  v = fmaxf(v, 0.f);
                if (STORE == 0) {
                    ((float*)Cp)[(size_t)row * N + col] = v;
                } else {
                    int b = row / 8400, pix = row - b * 8400;
                    int h = col >> 5, hd = col & 31;
                    ((u16*)Cp)[(((size_t)(b * 8 + h)) * 8400 + pix) * 32 + hd] = f2bf(v);
                }
            }
        }
    }
}

// ---------- MHA: per (b,h,half) block; K f32 + V bf16 staged in LDS ----------
__global__ __launch_bounds__(192) void k_mha(const float* __restrict__ Qp, const float* __restrict__ Kp,
                                             const float* __restrict__ Vp, float* __restrict__ outp)
{
    __shared__ float Ksh[300 * 32];   // 38.4 KB
    __shared__ u16   Vsh[300 * 32];   // 19.2 KB
    int bh = blockIdx.x >> 1, half = blockIdx.x & 1;
    int b = bh >> 3, h = bh & 7;
    const float* Kg = Kp + (size_t)b * 300 * 256 + h * 32;
    const float* Vg = Vp + (size_t)b * 300 * 256 + h * 32;
    for (int i = threadIdx.x; i < 9600; i += 192) {
        int kk = i >> 5, dd = i & 31;
        Ksh[i] = Kg[(size_t)kk * 256 + dd];
        Vsh[i] = f2bf(Vg[(size_t)kk * 256 + dd]);
    }
    __syncthreads();
    int qi = threadIdx.x;
    if (qi >= 150) return;
    int q = half * 150 + qi;
    const float* qg = Qp + ((size_t)(b * 300 + q)) * 256 + h * 32;
    float qv[32];
#pragma unroll
    for (int d = 0; d < 32; d++) qv[d] = qg[d] * 0.17677669529663687f; // 1/sqrt(32)
    float mx = -1e30f;
    for (int kk = 0; kk < 300; kk++) {
        float s = 0.f;
        const float* kr = Ksh + kk * 32;
#pragma unroll
        for (int c = 0; c < 8; c++) {
            float4 k4 = *(const float4*)(kr + c * 4);
            s += qv[c*4+0]*k4.x + qv[c*4+1]*k4.y + qv[c*4+2]*k4.z + qv[c*4+3]*k4.w;
        }
        mx = fmaxf(mx, s);
    }
    float l = 0.f;
    float accv[32];
#pragma unroll
    for (int d = 0; d < 32; d++) accv[d] = 0.f;
    for (int kk = 0; kk < 300; kk++) {
        float s = 0.f;
        const float* kr = Ksh + kk * 32;
#pragma unroll
        for (int c = 0; c < 8; c++) {
            float4 k4 = *(const float4*)(kr + c * 4);
            s += qv[c*4+0]*k4.x + qv[c*4+1]*k4.y + qv[c*4+2]*k4.z + qv[c*4+3]*k4.w;
        }
        float p = __expf(s - mx);
        l += p;
        const u16* vr = Vsh + kk * 32;
#pragma unroll
        for (int c = 0; c < 4; c++) {
            uint4 vv = *(const uint4*)(vr + c * 8);
            accv[c*8+0] += p * bf2f((u16)(vv.x & 0xffff));
            accv[c*8+1] += p * bf2f((u16)(vv.x >> 16));
            accv[c*8+2] += p * bf2f((u16)(vv.y & 0xffff));
            accv[c*8+3] += p * bf2f((u16)(vv.y >> 16));
            accv[c*8+4] += p * bf2f((u16)(vv.z & 0xffff));
            accv[c*8+5] += p * bf2f((u16)(vv.z >> 16));
            accv[c*8+6] += p * bf2f((u16)(vv.w & 0xffff));
            accv[c*8+7] += p * bf2f((u16)(vv.w >> 16));
        }
    }
    float inv = 1.f / l;
    float* op = outp + ((size_t)(b * 300 + q)) * 256 + h * 32;
#pragma unroll
    for (int d = 0; d < 32; d++) op[d] = accv[d] * inv;
}

// ---------- LayerNorm: one wave per row of 256 ----------
__global__ __launch_bounds__(256) void k_ln(const float* __restrict__ x, const float* __restrict__ g,
                                            const float* __restrict__ bb, float* __restrict__ out, int M)
{
    int row = blockIdx.x * 4 + (threadIdx.x >> 6);
    int lane = threadIdx.x & 63;
    if (row >= M) return;
    const float* xr = x + (size_t)row * 256;
    float4 v = *(const float4*)(xr + lane * 4);
    float s  = v.x + v.y + v.z + v.w;
    float s2 = v.x*v.x + v.y*v.y + v.z*v.z + v.w*v.w;
#pragma unroll
    for (int off = 32; off >= 1; off >>= 1) {
        s  += __shfl_xor(s, off);
        s2 += __shfl_xor(s2, off);
    }
    float m   = s * 0.00390625f;
    float var = s2 * 0.00390625f - m * m;
    float r   = rsqrtf(var + 1e-5f);
    float4 gv = *(const float4*)(g + lane * 4);
    float4 bv = *(const float4*)(bb + lane * 4);
    float4 o;
    o.x = (v.x - m) * r * gv.x + bv.x;
    o.y = (v.y - m) * r * gv.y + bv.y;
    o.z = (v.z - m) * r * gv.z + bv.z;
    o.w = (v.w - m) * r * gv.w + bv.w;
    *(float4*)(out + (size_t)row * 256 + lane * 4) = o;
}

// ---------- aw softmax over 12 per (b,q,h) ----------
__global__ void k_awsm(float* __restrict__ aw, int n)
{
    int g = blockIdx.x * 256 + threadIdx.x;
    if (g >= n) return;
    float* p = aw + (size_t)g * 12;
    float m = p[0];
#pragma unroll
    for (int i = 1; i < 12; i++) m = fmaxf(m, p[i]);
    float e[12]; float s = 0.f;
#pragma unroll
    for (int i = 0; i < 12; i++) { e[i] = __expf(p[i] - m); s += e[i]; }
    float inv = 1.f / s;
#pragma unroll
    for (int i = 0; i < 12; i++) p[i] = e[i] * inv;
}

// ---------- deformable sampling: lane = channel (32/item), 8 items/block ----------
__global__ __launch_bounds__(256) void k_msda(const u16* __restrict__ value, const float* __restrict__ off,
                                              const float* __restrict__ aw, const float* __restrict__ ref,
                                              float* __restrict__ samp)
{
    int it = blockIdx.x * 8 + (threadIdx.x >> 5);
    int d  = threadIdx.x & 31;
    int h = it & 7, row = it >> 3;
    int b = row / 300;
    const float* rf = ref + (size_t)row * 4;
    float rx = rf[0], ry = rf[1];
    float rw = rf[2] * 0.125f, rh = rf[3] * 0.125f;   // /P * 0.5
    const float* offp = off + (size_t)row * 192 + h * 24;
    const float* awp  = aw  + (size_t)row * 96  + h * 12;
    const u16* vb = value + ((size_t)(b * 8 + h)) * 8400 * 32 + d;
    const int HW[3] = {80, 40, 20};
    const int st[3] = {0, 6400, 8000};
    float acc = 0.f;
#pragma unroll
    for (int lv = 0; lv < 3; lv++) {
        int Wl = HW[lv], Hl = HW[lv];
        float Wf = (float)Wl, Hf = (float)Hl;
#pragma unroll
        for (int p = 0; p < 4; p++) {
            float a = awp[lv * 4 + p];
            float x = (rx + offp[lv*8 + p*2]     * rw) * Wf - 0.5f;
            float y = (ry + offp[lv*8 + p*2 + 1] * rh) * Hf - 0.5f;
            float xf = floorf(x), yf = floorf(y);
            float wx = x - xf, wy = y - yf;
            int x0 = (int)xf, y0 = (int)yf;
#pragma unroll
            for (int t = 0; t < 4; t++) {
                int xx = x0 + (t & 1), yy = y0 + (t >> 1);
                if (xx >= 0 && xx < Wl && yy >= 0 && yy < Hl) {
                    float w = ((t & 1) ? wx : 1.f - wx) * ((t >> 1) ? wy : 1.f - wy);
                    acc += a * w * bf2f(vb[(size_t)(st[lv] + yy * Wl + xx) * 32]);
                }
            }
        }
    }
    samp[(size_t)row * 256 + h * 32 + d] = acc;
}

// ---------- qpe hidden: relu(ref(4) @ W1(4,512) + b1) ----------
__global__ void k_qpe_hidden(const float* __restrict__ ref, const float* __restrict__ W1,
                             const float* __restrict__ b1, float* __restrict__ hid)
{
    int idx = blockIdx.x * 256 + threadIdx.x;
    if (idx >= 4800 * 512) return;
    int row = idx >> 9, col = idx & 511;
    const float* r = ref + (size_t)row * 4;
    float v = b1[col] + r[0]*W1[col] + r[1]*W1[512+col] + r[2]*W1[1024+col] + r[3]*W1[1536+col];
    hid[idx] = fmaxf(v, 0.f);
}

// ---------- bbox tail: bb2(256) @ W3(256,4) + b3, ref = sigmoid(. + inv_sig(ref)) ----------
__global__ __launch_bounds__(64) void k_bb3(const float* __restrict__ bb2, const float* __restrict__ W3,
                                            const float* __restrict__ b3, float* __restrict__ ref)
{
    int row = blockIdx.x;
    int lane = threadIdx.x;
    const float* xr = bb2 + (size_t)row * 256;
    float s0 = 0, s1 = 0, s2 = 0, s3 = 0;
#pragma unroll
    for (int k = lane; k < 256; k += 64) {
        float xv = xr[k];
        float4 w = *(const float4*)(W3 + k * 4);
        s0 += xv * w.x; s1 += xv * w.y; s2 += xv * w.z; s3 += xv * w.w;
    }
#pragma unroll
    for (int off = 32; off >= 1; off >>= 1) {
        s0 += __shfl_xor(s0, off); s1 += __shfl_xor(s1, off);
        s2 += __shfl_xor(s2, off); s3 += __shfl_xor(s3, off);
    }
    if (lane == 0) {
        float sv[4] = {s0, s1, s2, s3};
        float* rr = ref + (size_t)row * 4;
#pragma unroll
        for (int j = 0; j < 4; j++) {
            float v = sv[j] + b3[j];
            float o = rr[j];
            o = fminf(fmaxf(o, 1e-5f), 1.f - 1e-5f);
            float inv = logf(o / (1.f - o));
            rr[j] = 1.f / (1.f + expf(-(v + inv)));
        }
    }
}

// ---------- small utility kernels ----------
__global__ void k_cvt_bf16(const float* __restrict__ in, u16* __restrict__ out, int n4)
{
    int i = blockIdx.x * 256 + threadIdx.x;
    if (i >= n4) return;
    float4 v = ((const float4*)in)[i];
    ushort4 h; h.x = f2bf(v.x); h.y = f2bf(v.y); h.z = f2bf(v.z); h.w = f2bf(v.w);
    ((ushort4*)out)[i] = h;
}
__global__ void k_copy4(const float* __restrict__ in, float* __restrict__ out, int n4)
{
    int i = blockIdx.x * 256 + threadIdx.x;
    if (i >= n4) return;
    ((float4*)out)[i] = ((const float4*)in)[i];
}
__global__ void k_sigmoid(const float* __restrict__ in, float* __restrict__ out, int n)
{
    int i = blockIdx.x * 256 + threadIdx.x;
    if (i >= n) return;
    out[i] = 1.f / (1.f + __expf(-in[i]));
}

// ---------- host-side launch helpers ----------
static inline dim3 ggrid(int M, int N) { return dim3((M + 63) / 64, (N + 127) / 128); }

static void gemm_plain(const float* A, const float* Bw, const float* bias, float* C,
                       int M, int N, int K, hipStream_t s) {
    k_gemm<0, 0, false, false><<<ggrid(M, N), 256, 0, s>>>((const void*)A, nullptr, Bw, bias, nullptr, (void*)C, M, N, K);
}
static void gemm_add(const float* A, const float* A2, const float* Bw, const float* bias, float* C,
                     int M, int N, int K, hipStream_t s) {
    k_gemm<1, 0, false, false><<<ggrid(M, N), 256, 0, s>>>((const void*)A, A2, Bw, bias, nullptr, (void*)C, M, N, K);
}
static void gemm_resid(const float* A, const float* Bw, const float* bias, const float* resid, float* C,
                       int M, int N, int K, hipStream_t s) {
    k_gemm<0, 0, false, true><<<ggrid(M, N), 256, 0, s>>>((const void*)A, nullptr, Bw, bias, resid, (void*)C, M, N, K);
}
static void gemm_relu(const float* A, const float* Bw, const float* bias, float* C,
                      int M, int N, int K, hipStream_t s) {
    k_gemm<0, 0, true, false><<<ggrid(M, N), 256, 0, s>>>((const void*)A, nullptr, Bw, bias, nullptr, (void*)C, M, N, K);
}
static void gemm_value(const u16* A, const float* Bw, const float* bias, u16* C, hipStream_t s) {
    k_gemm<2, 1, false, false><<<ggrid(134400, 256), 256, 0, s>>>((const void*)A, nullptr, Bw, bias, nullptr, (void*)C, 134400, 256, 256);
}

extern "C" void kernel_launch(void* const* d_in, const int* in_sizes, int n_in,
                              void* d_out, int out_size, void* d_ws, size_t ws_size,
                              hipStream_t stream)
{
    const float* tgt       = (const float*)d_in[0];
    const float* ref_unact = (const float*)d_in[1];
    const float* memory    = (const float*)d_in[2];
    const float* self_Wq = (const float*)d_in[4];
    const float* self_bq = (const float*)d_in[5];
    const float* self_Wk = (const float*)d_in[6];
    const float* self_bk = (const float*)d_in[7];
    const float* self_Wv = (const float*)d_in[8];
    const float* self_bv = (const float*)d_in[9];
    const float* self_Wo = (const float*)d_in[10];
    const float* self_bo = (const float*)d_in[11];
    const float* ln1_g = (const float*)d_in[12];
    const float* ln1_b = (const float*)d_in[13];
    const float* ln2_g = (const float*)d_in[14];
    const float* ln2_b = (const float*)d_in[15];
    const float* ln3_g = (const float*)d_in[16];
    const float* ln3_b = (const float*)d_in[17];
    const float* off_W = (const float*)d_in[18];
    const float* off_b = (const float*)d_in[19];
    const float* aw_W  = (const float*)d_in[20];
    const float* aw_b  = (const float*)d_in[21];
    const float* val_W = (const float*)d_in[22];
    const float* val_b = (const float*)d_in[23];
    const float* out_W = (const float*)d_in[24];
    const float* out_b = (const float*)d_in[25];
    const float* ffn_W1 = (const float*)d_in[26];
    const float* ffn_b1 = (const float*)d_in[27];
    const float* ffn_W2 = (const float*)d_in[28];
    const float* ffn_b2 = (const float*)d_in[29];
    const float* qph_W1 = (const float*)d_in[30];
    const float* qph_b1 = (const float*)d_in[31];
    const float* qph_W2 = (const float*)d_in[32];
    const float* qph_b2 = (const float*)d_in[33];
    const float* bb_W1 = (const float*)d_in[34];
    const float* bb_b1 = (const float*)d_in[35];
    const float* bb_W2 = (const float*)d_in[36];
    const float* bb_b2 = (const float*)d_in[37];
    const float* bb_W3 = (const float*)d_in[38];
    const float* bb_b3 = (const float*)d_in[39];
    const float* sc_W  = (const float*)d_in[40];
    const float* sc_b  = (const float*)d_in[41];
    float* out_f = (float*)d_out;

    // ---- workspace layout (bytes) ----
    char* w = (char*)d_ws;
    u16* mem_bf  = (u16*)(w + 0);            // 134400*256 bf16 = 68,812,800
    u16* value   = (u16*)(w + 68812800);     // 16*8*8400*32 bf16 = 68,812,800
    const size_t F0 = 137625600;
    float* ws_out  = (float*)(w + F0);
    float* ws_tmp  = (float*)(w + F0 +  4915200);
    float* ws_qpe  = (float*)(w + F0 +  9830400);
    float* ws_hid  = (float*)(w + F0 + 14745600);   // 4800x512
    float* ws_q    = (float*)(w + F0 + 24576000);
    float* ws_k    = (float*)(w + F0 + 29491200);
    float* ws_v    = (float*)(w + F0 + 34406400);
    float* ws_attn = (float*)(w + F0 + 39321600);
    float* ws_offb = (float*)(w + F0 + 44236800);   // 4800x192
    float* ws_aw   = (float*)(w + F0 + 47923200);   // 4800x96
    float* ws_samp = (float*)(w + F0 + 49766400);
    float* ws_ffn  = (float*)(w + F0 + 54681600);   // 4800x1024
    float* ws_bb1  = (float*)(w + F0 + 74342400);
    float* ws_bb2  = (float*)(w + F0 + 79257600);
    float* ws_ref  = (float*)(w + F0 + 84172800);   // 4800x4

    // ---- init ----
    k_cvt_bf16<<<33600, 256, 0, stream>>>(memory, mem_bf, 8601600);      // 34.4M elems /4
    k_copy4  <<<1200,  256, 0, stream>>>(tgt, ws_out, 307200);           // out = tgt
    k_sigmoid<<<75,    256, 0, stream>>>(ref_unact, ws_ref, 19200);      // ref = sigmoid(.)

    for (int l = 0; l < 6; l++) {
        const float* Wq = self_Wq + (size_t)l * 65536; const float* bq = self_bq + l * 256;
        const float* Wk = self_Wk + (size_t)l * 65536; const float* bk = self_bk + l * 256;
        const float* Wv = self_Wv + (size_t)l * 65536; const float* bv = self_bv + l * 256;
        const float* Wo = self_Wo + (size_t)l * 65536; const float* bo = self_bo + l * 256;

        // qpe = relu(ref @ qph_W1 + b1) @ qph_W2 + b2
        k_qpe_hidden<<<9600, 256, 0, stream>>>(ws_ref, qph_W1, qph_b1, ws_hid);
        gemm_plain(ws_hid, qph_W2, qph_b2, ws_qpe, 4800, 256, 512, stream);

        // self-attention
        gemm_add(ws_out, ws_qpe, Wq, bq, ws_q, 4800, 256, 256, stream);
        gemm_add(ws_out, ws_qpe, Wk, bk, ws_k, 4800, 256, 256, stream);
        gemm_plain(ws_out, Wv, bv, ws_v, 4800, 256, 256, stream);
        k_mha<<<256, 192, 0, stream>>>(ws_q, ws_k, ws_v, ws_attn);
        gemm_resid(ws_attn, Wo, bo, ws_out, ws_tmp, 4800, 256, 256, stream);
        k_ln<<<1200, 256, 0, stream>>>(ws_tmp, ln1_g + l * 256, ln1_b + l * 256, ws_out, 4800);

        // value projection for this layer (bf16, (b,h,pix,hd) layout)
        gemm_value(mem_bf, val_W + (size_t)l * 65536, val_b + l * 256, value, stream);

        // deformable attention
        gemm_add(ws_out, ws_qpe, off_W + (size_t)l * 49152, off_b + l * 192, ws_offb, 4800, 192, 256, stream);
        gemm_add(ws_out, ws_qpe, aw_W  + (size_t)l * 24576, aw_b  + l * 96,  ws_aw,   4800, 96,  256, stream);
        k_awsm<<<150, 256, 0, stream>>>(ws_aw, 38400);
        k_msda<<<4800, 256, 0, stream>>>(value, ws_offb, ws_aw, ws_ref, ws_samp);
        gemm_resid(ws_samp, out_W + (size_t)l * 65536, out_b + l * 256, ws_out, ws_tmp, 4800, 256, 256, stream);
        k_ln<<<1200, 256, 0, stream>>>(ws_tmp, ln2_g + l * 256, ln2_b + l * 256, ws_out, 4800);

        // FFN
        gemm_relu(ws_out, ffn_W1 + (size_t)l * 262144, ffn_b1 + l * 1024, ws_ffn, 4800, 1024, 256, stream);
        gemm_resid(ws_ffn, ffn_W2 + (size_t)l * 262144, ffn_b2 + l * 256, ws_out, ws_tmp, 4800, 256, 1024, stream);
        k_ln<<<1200, 256, 0, stream>>>(ws_tmp, ln3_g + l * 256, ln3_b + l * 256, ws_out, 4800);

        // bbox head + ref update
        gemm_relu(ws_out, bb_W1 + (size_t)l * 65536, bb_b1 + l * 256, ws_bb1, 4800, 256, 256, stream);
        gemm_relu(ws_bb1, bb_W2 + (size_t)l * 65536, bb_b2 + l * 256, ws_bb2, 4800, 256, 256, stream);
        k_bb3<<<4800, 64, 0, stream>>>(ws_bb2, bb_W3 + (size_t)l * 1024, bb_b3 + l * 4, ws_ref);
    }

    // outputs: ref (19200 f32) then logits (4800x80 f32)
    k_copy4<<<19, 256, 0, stream>>>(ws_ref, out_f, 4800);
    gemm_plain(ws_out, sc_W + (size_t)5 * 20480, sc_b + 5 * 80, out_f + 19200, 4800, 80, 256, stream);
}

// Round 4
// 3085.797 us; speedup vs baseline: 1.6735x; 1.6735x over previous
//
#include <hip/hip_runtime.h>

#define DI __device__ __forceinline__

typedef __attribute__((ext_vector_type(8))) short short8;
typedef __attribute__((ext_vector_type(4))) float f32x4;
typedef unsigned short u16;

// ---------- helpers ----------
DI u16 f2bf(float f) {
    union { float f; unsigned u; } v; v.f = f;
    unsigned u = v.u;
    return (u16)((u + 0x7fffu + ((u >> 16) & 1u)) >> 16);   // RNE
}
DI float bf2f(u16 h) {
    union { unsigned u; float f; } v; v.u = ((unsigned)h) << 16;
    return v.f;
}
// byte offset of 16B slot `slot` (0..3) of row `row` in a [rows][32]bf16 tile,
// XOR-swizzled: slot ^= (row>>1)&3 -> fragment reads/writes are 2-way (free).
DI int lds_off(int row, int slot) {
    return row * 64 + (((slot ^ ((row >> 1) & 3)) << 4));
}

// ---------- weight transpose+convert: Wt[N][K] bf16 = W[K][N] f32 ----------
// grid (K/32, ceil(N/32), L); 256 threads
__global__ __launch_bounds__(256) void k_wt(const float* __restrict__ W, u16* __restrict__ Wt,
                                            int K, int N)
{
    __shared__ u16 t[32][33];
    const int tid = threadIdx.x;
    const int kt = blockIdx.x * 32, nt = blockIdx.y * 32;
    const float* Wl = W + (size_t)blockIdx.z * K * N;
    u16* Wtl = Wt + (size_t)blockIdx.z * K * N;
#pragma unroll
    for (int i = 0; i < 4; i++) {
        int k = kt + (tid >> 5) + i * 8;
        int n = nt + (tid & 31);
        float v = (n < N) ? Wl[(size_t)k * N + n] : 0.f;
        t[tid & 31][(tid >> 5) + i * 8] = f2bf(v);
    }
    __syncthreads();
#pragma unroll
    for (int i = 0; i < 4; i++) {
        int n = nt + (tid >> 5) + i * 8;
        int k = kt + (tid & 31);
        if (n < N) Wtl[(size_t)n * K + k] = t[(tid >> 5) + i * 8][tid & 31];
    }
}

// ---------- generic MFMA GEMM: C[M,N] = A[M,K] @ B[K,N] (+bias,+resid,relu) ----------
// TN=128, K-step 32. 256 threads = 4 waves (2x2); wave tile (TM/2) x 64.
// B passed pre-transposed bf16: Bt[N][K].
// AMODE: 0 = A f32; 1 = A f32 = A0+A1 (elementwise)
// STORE: 0 = f32 linear ldc=N; 1 = bf16 "value layout" ((b*8+h)*8400+pix)*32+hd
template<int TM, int AMODE, int STORE, bool RELU, bool RESID>
__global__ __launch_bounds__(256) void k_gemm(
    const float* __restrict__ Ap, const float* __restrict__ A2,
    const u16* __restrict__ Bt, const float* __restrict__ bias,
    const float* __restrict__ resid, void* __restrict__ Cp,
    int M, int N, int K)
{
    constexpr int MI = TM / 32;
    __shared__ alignas(16) char Asm[TM * 64];    // TM rows x 32 bf16
    __shared__ alignas(16) char Bsm[128 * 64];   // 128 n-rows x 32 bf16
    const int tid  = threadIdx.x;
    const int lane = tid & 63;
    const int wave = tid >> 6;
    const int wr = wave >> 1, wc = wave & 1;
    const int m0 = blockIdx.x * TM, n0 = blockIdx.y * 128;

    f32x4 acc[MI][4] = {};

    for (int kb = 0; kb < K; kb += 32) {
        // ---- stage A tile (TM x 32) f32 -> bf16; 8B writes, conflict-free ----
        constexpr int AIT = (TM * 8) / 256;
#pragma unroll
        for (int j = 0; j < AIT; j++) {
            int flat = tid + j * 256;
            int r = flat >> 3, kq = flat & 7;       // kq*4 = k offset
            int grow = m0 + r; if (grow > M - 1) grow = M - 1;
            const float* p = Ap + (size_t)grow * K + kb + (kq << 2);
            float4 v = *(const float4*)p;
            if (AMODE == 1) {
                float4 w = *(const float4*)(A2 + (size_t)grow * K + kb + (kq << 2));
                v.x += w.x; v.y += w.y; v.z += w.z; v.w += w.w;
            }
            ushort4 h; h.x = f2bf(v.x); h.y = f2bf(v.y); h.z = f2bf(v.z); h.w = f2bf(v.w);
            *(ushort4*)(Asm + lds_off(r, kq >> 1) + ((kq & 1) << 3)) = h;
        }
        // ---- stage B tile (128 n x 32 k) from Bt[N][K]: 16B load + 16B write ----
#pragma unroll
        for (int j = 0; j < 2; j++) {
            int item = tid + j * 256;               // 0..511
            int n = item >> 2, kq = item & 3;
            int gn = n0 + n; if (gn > N - 1) gn = N - 1;
            uint4 v = *(const uint4*)(Bt + (size_t)gn * K + kb + (kq << 3));
            *(uint4*)(Bsm + lds_off(n, kq)) = v;
        }
        __syncthreads();

        short8 af[MI], bfr[4];
#pragma unroll
        for (int mi = 0; mi < MI; mi++) {
            int r = wr * (TM / 2) + (mi << 4) + (lane & 15);
            af[mi] = *(const short8*)(Asm + lds_off(r, lane >> 4));
        }
#pragma unroll
        for (int ni = 0; ni < 4; ni++) {
            int c = (wc << 6) + (ni << 4) + (lane & 15);
            bfr[ni] = *(const short8*)(Bsm + lds_off(c, lane >> 4));
        }
#pragma unroll
        for (int mi = 0; mi < MI; mi++)
#pragma unroll
            for (int ni = 0; ni < 4; ni++)
                acc[mi][ni] = __builtin_amdgcn_mfma_f32_16x16x32_bf16(af[mi], bfr[ni], acc[mi][ni], 0, 0, 0);
        __syncthreads();
    }

    // ---- epilogue: C/D layout col=lane&15, row=(lane>>4)*4+e ----
    const int cl = lane & 15, rb = (lane >> 4) << 2;
#pragma unroll
    for (int mi = 0; mi < MI; mi++) {
#pragma unroll
        for (int ni = 0; ni < 4; ni++) {
            int col = n0 + (wc << 6) + (ni << 4) + cl;
            if (col >= N) continue;
            float bv = bias[col];
#pragma unroll
            for (int e = 0; e < 4; e++) {
                int row = m0 + wr * (TM / 2) + (mi << 4) + rb + e;
                if (row >= M) continue;
                float v = acc[mi][ni][e] + bv;
                if (RESID) v += resid[(size_t)row * N + col];
                if (RELU)  v = fmaxf(v, 0.f);
                if (STORE == 0) {
                    ((float*)Cp)[(size_t)row * N + col] = v;
                } else {
                    int b = row / 8400, pix = row - b * 8400;
                    int h = col >> 5, hd = col & 31;
                    ((u16*)Cp)[(((size_t)(b * 8 + h)) * 8400 + pix) * 32 + hd] = f2bf(v);
                }
            }
        }
    }
}

// ---------- MHA: per (b,h,half) block; K f32 + V bf16 staged in LDS ----------
__global__ __launch_bounds__(192) void k_mha(const float* __restrict__ Qp, const float* __restrict__ Kp,
                                             const float* __restrict__ Vp, float* __restrict__ outp)
{
    __shared__ float Ksh[300 * 32];
    __shared__ u16   Vsh[300 * 32];
    int bh = blockIdx.x >> 1, half = blockIdx.x & 1;
    int b = bh >> 3, h = bh & 7;
    const float* Kg = Kp + (size_t)b * 300 * 256 + h * 32;
    const float* Vg = Vp + (size_t)b * 300 * 256 + h * 32;
    for (int i = threadIdx.x; i < 9600; i += 192) {
        int kk = i >> 5, dd = i & 31;
        Ksh[i] = Kg[(size_t)kk * 256 + dd];
        Vsh[i] = f2bf(Vg[(size_t)kk * 256 + dd]);
    }
    __syncthreads();
    int qi = threadIdx.x;
    if (qi >= 150) return;
    int q = half * 150 + qi;
    const float* qg = Qp + ((size_t)(b * 300 + q)) * 256 + h * 32;
    float qv[32];
#pragma unroll
    for (int d = 0; d < 32; d++) qv[d] = qg[d] * 0.17677669529663687f; // 1/sqrt(32)
    float mx = -1e30f;
    for (int kk = 0; kk < 300; kk++) {
        float s = 0.f;
        const float* kr = Ksh + kk * 32;
#pragma unroll
        for (int c = 0; c < 8; c++) {
            float4 k4 = *(const float4*)(kr + c * 4);
            s += qv[c*4+0]*k4.x + qv[c*4+1]*k4.y + qv[c*4+2]*k4.z + qv[c*4+3]*k4.w;
        }
        mx = fmaxf(mx, s);
    }
    float l = 0.f;
    float accv[32];
#pragma unroll
    for (int d = 0; d < 32; d++) accv[d] = 0.f;
    for (int kk = 0; kk < 300; kk++) {
        float s = 0.f;
        const float* kr = Ksh + kk * 32;
#pragma unroll
        for (int c = 0; c < 8; c++) {
            float4 k4 = *(const float4*)(kr + c * 4);
            s += qv[c*4+0]*k4.x + qv[c*4+1]*k4.y + qv[c*4+2]*k4.z + qv[c*4+3]*k4.w;
        }
        float p = __expf(s - mx);
        l += p;
        const u16* vr = Vsh + kk * 32;
#pragma unroll
        for (int c = 0; c < 4; c++) {
            uint4 vv = *(const uint4*)(vr + c * 8);
            accv[c*8+0] += p * bf2f((u16)(vv.x & 0xffff));
            accv[c*8+1] += p * bf2f((u16)(vv.x >> 16));
            accv[c*8+2] += p * bf2f((u16)(vv.y & 0xffff));
            accv[c*8+3] += p * bf2f((u16)(vv.y >> 16));
            accv[c*8+4] += p * bf2f((u16)(vv.z & 0xffff));
            accv[c*8+5] += p * bf2f((u16)(vv.z >> 16));
            accv[c*8+6] += p * bf2f((u16)(vv.w & 0xffff));
            accv[c*8+7] += p * bf2f((u16)(vv.w >> 16));
        }
    }
    float inv = 1.f / l;
    float* op = outp + ((size_t)(b * 300 + q)) * 256 + h * 32;
#pragma unroll
    for (int d = 0; d < 32; d++) op[d] = accv[d] * inv;
}

// ---------- LayerNorm: one wave per row of 256 ----------
__global__ __launch_bounds__(256) void k_ln(const float* __restrict__ x, const float* __restrict__ g,
                                            const float* __restrict__ bb, float* __restrict__ out, int M)
{
    int row = blockIdx.x * 4 + (threadIdx.x >> 6);
    int lane = threadIdx.x & 63;
    if (row >= M) return;
    const float* xr = x + (size_t)row * 256;
    float4 v = *(const float4*)(xr + lane * 4);
    float s  = v.x + v.y + v.z + v.w;
    float s2 = v.x*v.x + v.y*v.y + v.z*v.z + v.w*v.w;
#pragma unroll
    for (int off = 32; off >= 1; off >>= 1) {
        s  += __shfl_xor(s, off);
        s2 += __shfl_xor(s2, off);
    }
    float m   = s * 0.00390625f;
    float var = s2 * 0.00390625f - m * m;
    float r   = rsqrtf(var + 1e-5f);
    float4 gv = *(const float4*)(g + lane * 4);
    float4 bv = *(const float4*)(bb + lane * 4);
    float4 o;
    o.x = (v.x - m) * r * gv.x + bv.x;
    o.y = (v.y - m) * r * gv.y + bv.y;
    o.z = (v.z - m) * r * gv.z + bv.z;
    o.w = (v.w - m) * r * gv.w + bv.w;
    *(float4*)(out + (size_t)row * 256 + lane * 4) = o;
}

// ---------- aw softmax over 12 per (b,q,h) ----------
__global__ void k_awsm(float* __restrict__ aw, int n)
{
    int g = blockIdx.x * 256 + threadIdx.x;
    if (g >= n) return;
    float* p = aw + (size_t)g * 12;
    float m = p[0];
#pragma unroll
    for (int i = 1; i < 12; i++) m = fmaxf(m, p[i]);
    float e[12]; float s = 0.f;
#pragma unroll
    for (int i = 0; i < 12; i++) { e[i] = __expf(p[i] - m); s += e[i]; }
    float inv = 1.f / s;
#pragma unroll
    for (int i = 0; i < 12; i++) p[i] = e[i] * inv;
}

// ---------- deformable sampling: lane = channel (32/item), 8 items/block ----------
__global__ __launch_bounds__(256) void k_msda(const u16* __restrict__ value, const float* __restrict__ off,
                                              const float* __restrict__ aw, const float* __restrict__ ref,
                                              float* __restrict__ samp)
{
    int it = blockIdx.x * 8 + (threadIdx.x >> 5);
    int d  = threadIdx.x & 31;
    int h = it & 7, row = it >> 3;
    int b = row / 300;
    const float* rf = ref + (size_t)row * 4;
    float rx = rf[0], ry = rf[1];
    float rw = rf[2] * 0.125f, rh = rf[3] * 0.125f;   // /P * 0.5
    const float* offp = off + (size_t)row * 192 + h * 24;
    const float* awp  = aw  + (size_t)row * 96  + h * 12;
    const u16* vb = value + ((size_t)(b * 8 + h)) * 8400 * 32 + d;
    const int HW[3] = {80, 40, 20};
    const int st[3] = {0, 6400, 8000};
    float acc = 0.f;
#pragma unroll
    for (int lv = 0; lv < 3; lv++) {
        int Wl = HW[lv], Hl = HW[lv];
        float Wf = (float)Wl, Hf = (float)Hl;
#pragma unroll
        for (int p = 0; p < 4; p++) {
            float a = awp[lv * 4 + p];
            float x = (rx + offp[lv*8 + p*2]     * rw) * Wf - 0.5f;
            float y = (ry + offp[lv*8 + p*2 + 1] * rh) * Hf - 0.5f;
            float xf = floorf(x), yf = floorf(y);
            float wx = x - xf, wy = y - yf;
            int x0 = (int)xf, y0 = (int)yf;
#pragma unroll
            for (int t = 0; t < 4; t++) {
                int xx = x0 + (t & 1), yy = y0 + (t >> 1);
                if (xx >= 0 && xx < Wl && yy >= 0 && yy < Hl) {
                    float w = ((t & 1) ? wx : 1.f - wx) * ((t >> 1) ? wy : 1.f - wy);
                    acc += a * w * bf2f(vb[(size_t)(st[lv] + yy * Wl + xx) * 32]);
                }
            }
        }
    }
    samp[(size_t)row * 256 + h * 32 + d] = acc;
}

// ---------- qpe hidden: relu(ref(4) @ W1(4,512) + b1) ----------
__global__ void k_qpe_hidden(const float* __restrict__ ref, const float* __restrict__ W1,
                             const float* __restrict__ b1, float* __restrict__ hid)
{
    int idx = blockIdx.x * 256 + threadIdx.x;
    if (idx >= 4800 * 512) return;
    int row = idx >> 9, col = idx & 511;
    const float* r = ref + (size_t)row * 4;
    float v = b1[col] + r[0]*W1[col] + r[1]*W1[512+col] + r[2]*W1[1024+col] + r[3]*W1[1536+col];
    hid[idx] = fmaxf(v, 0.f);
}

// ---------- bbox tail: bb2(256) @ W3(256,4) + b3, ref = sigmoid(. + inv_sig(ref)) ----------
__global__ __launch_bounds__(64) void k_bb3(const float* __restrict__ bb2, const float* __restrict__ W3,
                                            const float* __restrict__ b3, float* __restrict__ ref)
{
    int row = blockIdx.x;
    int lane = threadIdx.x;
    const float* xr = bb2 + (size_t)row * 256;
    float s0 = 0, s1 = 0, s2 = 0, s3 = 0;
#pragma unroll
    for (int k = lane; k < 256; k += 64) {
        float xv = xr[k];
        float4 w = *(const float4*)(W3 + k * 4);
        s0 += xv * w.x; s1 += xv * w.y; s2 += xv * w.z; s3 += xv * w.w;
    }
#pragma unroll
    for (int off = 32; off >= 1; off >>= 1) {
        s0 += __shfl_xor(s0, off); s1 += __shfl_xor(s1, off);
        s2 += __shfl_xor(s2, off); s3 += __shfl_xor(s3, off);
    }
    if (lane == 0) {
        float sv[4] = {s0, s1, s2, s3};
        float* rr = ref + (size_t)row * 4;
#pragma unroll
        for (int j = 0; j < 4; j++) {
            float v = sv[j] + b3[j];
            float o = rr[j];
            o = fminf(fmaxf(o, 1e-5f), 1.f - 1e-5f);
            float inv = logf(o / (1.f - o));
            rr[j] = 1.f / (1.f + expf(-(v + inv)));
        }
    }
}

// ---------- small utility kernels ----------
__global__ void k_copy4(const float* __restrict__ in, float* __restrict__ out, int n4)
{
    int i = blockIdx.x * 256 + threadIdx.x;
    if (i >= n4) return;
    ((float4*)out)[i] = ((const float4*)in)[i];
}
__global__ void k_sigmoid(const float* __restrict__ in, float* __restrict__ out, int n)
{
    int i = blockIdx.x * 256 + threadIdx.x;
    if (i >= n) return;
    out[i] = 1.f / (1.f + __expf(-in[i]));
}

// ---------- host-side launch helpers ----------
static inline dim3 g32(int M, int N) { return dim3((M + 31) / 32, (N + 127) / 128); }

static void gemm_plain(const float* A, const u16* Bt, const float* bias, float* C,
                       int M, int N, int K, hipStream_t s) {
    k_gemm<32, 0, 0, false, false><<<g32(M, N), 256, 0, s>>>(A, nullptr, Bt, bias, nullptr, (void*)C, M, N, K);
}
static void gemm_add(const float* A, const float* A2, const u16* Bt, const float* bias, float* C,
                     int M, int N, int K, hipStream_t s) {
    k_gemm<32, 1, 0, false, false><<<g32(M, N), 256, 0, s>>>(A, A2, Bt, bias, nullptr, (void*)C, M, N, K);
}
static void gemm_resid(const float* A, const u16* Bt, const float* bias, const float* resid, float* C,
                       int M, int N, int K, hipStream_t s) {
    k_gemm<32, 0, 0, false, true><<<g32(M, N), 256, 0, s>>>(A, nullptr, Bt, bias, resid, (void*)C, M, N, K);
}
static void gemm_relu(const float* A, const u16* Bt, const float* bias, float* C,
                      int M, int N, int K, hipStream_t s) {
    k_gemm<32, 0, 0, true, false><<<g32(M, N), 256, 0, s>>>(A, nullptr, Bt, bias, nullptr, (void*)C, M, N, K);
}
static void gemm_value(const float* A, const u16* Bt, const float* bias, u16* C, hipStream_t s) {
    k_gemm<64, 0, 1, false, false><<<dim3(2100, 2), 256, 0, s>>>(A, nullptr, Bt, bias, nullptr, (void*)C, 134400, 256, 256);
}

extern "C" void kernel_launch(void* const* d_in, const int* in_sizes, int n_in,
                              void* d_out, int out_size, void* d_ws, size_t ws_size,
                              hipStream_t stream)
{
    const float* tgt       = (const float*)d_in[0];
    const float* ref_unact = (const float*)d_in[1];
    const float* memory    = (const float*)d_in[2];
    const float* self_Wq = (const float*)d_in[4];
    const float* self_bq = (const float*)d_in[5];
    const float* self_Wk = (const float*)d_in[6];
    const float* self_bk = (const float*)d_in[7];
    const float* self_Wv = (const float*)d_in[8];
    const float* self_bv = (const float*)d_in[9];
    const float* self_Wo = (const float*)d_in[10];
    const float* self_bo = (const float*)d_in[11];
    const float* ln1_g = (const float*)d_in[12];
    const float* ln1_b = (const float*)d_in[13];
    const float* ln2_g = (const float*)d_in[14];
    const float* ln2_b = (const float*)d_in[15];
    const float* ln3_g = (const float*)d_in[16];
    const float* ln3_b = (const float*)d_in[17];
    const float* off_W = (const float*)d_in[18];
    const float* off_b = (const float*)d_in[19];
    const float* aw_W  = (const float*)d_in[20];
    const float* aw_b  = (const float*)d_in[21];
    const float* val_W = (const float*)d_in[22];
    const float* val_b = (const float*)d_in[23];
    const float* out_W = (const float*)d_in[24];
    const float* out_b = (const float*)d_in[25];
    const float* ffn_W1 = (const float*)d_in[26];
    const float* ffn_b1 = (const float*)d_in[27];
    const float* ffn_W2 = (const float*)d_in[28];
    const float* ffn_b2 = (const float*)d_in[29];
    const float* qph_W1 = (const float*)d_in[30];
    const float* qph_b1 = (const float*)d_in[31];
    const float* qph_W2 = (const float*)d_in[32];
    const float* qph_b2 = (const float*)d_in[33];
    const float* bb_W1 = (const float*)d_in[34];
    const float* bb_b1 = (const float*)d_in[35];
    const float* bb_W2 = (const float*)d_in[36];
    const float* bb_b2 = (const float*)d_in[37];
    const float* bb_W3 = (const float*)d_in[38];
    const float* bb_b3 = (const float*)d_in[39];
    const float* sc_W  = (const float*)d_in[40];
    const float* sc_b  = (const float*)d_in[41];
    float* out_f = (float*)d_out;

    // ---- workspace layout (bytes) ----
    char* w = (char*)d_ws;
    u16* value = (u16*)(w + 0);                 // 16*8*8400*32 bf16 = 68,812,800
    const size_t F0 = 68812800;
    float* ws_out  = (float*)(w + F0);
    float* ws_tmp  = (float*)(w + F0 +  4915200);
    float* ws_qpe  = (float*)(w + F0 +  9830400);
    float* ws_hid  = (float*)(w + F0 + 14745600);   // 4800x512
    float* ws_q    = (float*)(w + F0 + 24576000);
    float* ws_k    = (float*)(w + F0 + 29491200);
    float* ws_v    = (float*)(w + F0 + 34406400);
    float* ws_attn = (float*)(w + F0 + 39321600);
    float* ws_offb = (float*)(w + F0 + 44236800);   // 4800x192
    float* ws_aw   = (float*)(w + F0 + 47923200);   // 4800x96
    float* ws_samp = (float*)(w + F0 + 49766400);
    float* ws_ffn  = (float*)(w + F0 + 54681600);   // 4800x1024
    float* ws_bb1  = (float*)(w + F0 + 74342400);
    float* ws_bb2  = (float*)(w + F0 + 79257600);
    float* ws_ref  = (float*)(w + F0 + 84172800);   // 4800x4

    // ---- bf16 transposed weights (u16 elements), region after activations ----
    u16* wt = (u16*)(w + F0 + 84256800);
    u16* wt_q   = wt;                    // 6 x 65536
    u16* wt_k   = wt_q   + 393216;
    u16* wt_v   = wt_k   + 393216;
    u16* wt_o   = wt_v   + 393216;
    u16* wt_off = wt_o   + 393216;       // 6 x 49152
    u16* wt_aw  = wt_off + 294912;       // 6 x 24576
    u16* wt_val = wt_aw  + 147456;       // 6 x 65536
    u16* wt_out = wt_val + 393216;
    u16* wt_f1  = wt_out + 393216;       // 6 x 262144
    u16* wt_f2  = wt_f1  + 1572864;
    u16* wt_b1  = wt_f2  + 1572864;
    u16* wt_b2  = wt_b1  + 393216;
    u16* wt_qp2 = wt_b2  + 393216;       // 131072
    u16* wt_sc  = wt_qp2 + 131072;       // 20480

    // ---- init: weight transposes (batched over layers via grid.z) ----
    k_wt<<<dim3(8, 8, 6),   256, 0, stream>>>(self_Wq, wt_q,   256, 256);
    k_wt<<<dim3(8, 8, 6),   256, 0, stream>>>(self_Wk, wt_k,   256, 256);
    k_wt<<<dim3(8, 8, 6),   256, 0, stream>>>(self_Wv, wt_v,   256, 256);
    k_wt<<<dim3(8, 8, 6),   256, 0, stream>>>(self_Wo, wt_o,   256, 256);
    k_wt<<<dim3(8, 6, 6),   256, 0, stream>>>(off_W,   wt_off, 256, 192);
    k_wt<<<dim3(8, 3, 6),   256, 0, stream>>>(aw_W,    wt_aw,  256, 96);
    k_wt<<<dim3(8, 8, 6),   256, 0, stream>>>(val_W,   wt_val, 256, 256);
    k_wt<<<dim3(8, 8, 6),   256, 0, stream>>>(out_W,   wt_out, 256, 256);
    k_wt<<<dim3(8, 32, 6),  256, 0, stream>>>(ffn_W1,  wt_f1,  256, 1024);
    k_wt<<<dim3(32, 8, 6),  256, 0, stream>>>(ffn_W2,  wt_f2,  1024, 256);
    k_wt<<<dim3(8, 8, 6),   256, 0, stream>>>(bb_W1,   wt_b1,  256, 256);
    k_wt<<<dim3(8, 8, 6),   256, 0, stream>>>(bb_W2,   wt_b2,  256, 256);
    k_wt<<<dim3(16, 8, 1),  256, 0, stream>>>(qph_W2,  wt_qp2, 512, 256);
    k_wt<<<dim3(8, 3, 1),   256, 0, stream>>>(sc_W + (size_t)5 * 20480, wt_sc, 256, 80);

    k_copy4  <<<1200, 256, 0, stream>>>(tgt, ws_out, 307200);           // out = tgt
    k_sigmoid<<<75,   256, 0, stream>>>(ref_unact, ws_ref, 19200);      // ref = sigmoid(.)

    for (int l = 0; l < 6; l++) {
        // qpe = relu(ref @ qph_W1 + b1) @ qph_W2 + b2
        k_qpe_hidden<<<9600, 256, 0, stream>>>(ws_ref, qph_W1, qph_b1, ws_hid);
        gemm_plain(ws_hid, wt_qp2, qph_b2, ws_qpe, 4800, 256, 512, stream);

        // self-attention
        gemm_add(ws_out, ws_qpe, wt_q + (size_t)l * 65536, self_bq + l * 256, ws_q, 4800, 256, 256, stream);
        gemm_add(ws_out, ws_qpe, wt_k + (size_t)l * 65536, self_bk + l * 256, ws_k, 4800, 256, 256, stream);
        gemm_plain(ws_out, wt_v + (size_t)l * 65536, self_bv + l * 256, ws_v, 4800, 256, 256, stream);
        k_mha<<<256, 192, 0, stream>>>(ws_q, ws_k, ws_v, ws_attn);
        gemm_resid(ws_attn, wt_o + (size_t)l * 65536, self_bo + l * 256, ws_out, ws_tmp, 4800, 256, 256, stream);
        k_ln<<<1200, 256, 0, stream>>>(ws_tmp, ln1_g + l * 256, ln1_b + l * 256, ws_out, 4800);

        // value projection for this layer (bf16 out, (b,h,pix,hd) layout)
        gemm_value(memory, wt_val + (size_t)l * 65536, val_b + l * 256, value, stream);

        // deformable attention
        gemm_add(ws_out, ws_qpe, wt_off + (size_t)l * 49152, off_b + l * 192, ws_offb, 4800, 192, 256, stream);
        gemm_add(ws_out, ws_qpe, wt_aw + (size_t)l * 24576, aw_b + l * 96, ws_aw, 4800, 96, 256, stream);
        k_awsm<<<150, 256, 0, stream>>>(ws_aw, 38400);
        k_msda<<<4800, 256, 0, stream>>>(value, ws_offb, ws_aw, ws_ref, ws_samp);
        gemm_resid(ws_samp, wt_out + (size_t)l * 65536, out_b + l * 256, ws_out, ws_tmp, 4800, 256, 256, stream);
        k_ln<<<1200, 256, 0, stream>>>(ws_tmp, ln2_g + l * 256, ln2_b + l * 256, ws_out, 4800);

        // FFN
        gemm_relu(ws_out, wt_f1 + (size_t)l * 262144, ffn_b1 + l * 1024, ws_ffn, 4800, 1024, 256, stream);
        gemm_resid(ws_ffn, wt_f2 + (size_t)l * 262144, ffn_b2 + l * 256, ws_out, ws_tmp, 4800, 256, 1024, stream);
        k_ln<<<1200, 256, 0, stream>>>(ws_tmp, ln3_g + l * 256, ln3_b + l * 256, ws_out, 4800);

        // bbox head + ref update
        gemm_relu(ws_out, wt_b1 + (size_t)l * 65536, bb_b1 + l * 256, ws_bb1, 4800, 256, 256, stream);
        gemm_relu(ws_bb1, wt_b2 + (size_t)l * 65536, bb_b2 + l * 256, ws_bb2, 4800, 256, 256, stream);
        k_bb3<<<4800, 64, 0, stream>>>(ws_bb2, bb_W3 + (size_t)l * 1024, bb_b3 + l * 4, ws_ref);
    }

    // outputs: ref (19200 f32) then logits (4800x80 f32)
    k_copy4<<<19, 256, 0, stream>>>(ws_ref, out_f, 4800);
    gemm_plain(ws_out, wt_sc, sc_b + 5 * 80, out_f + 19200, 4800, 80, 256, stream);
}

// Round 6
// 2732.919 us; speedup vs baseline: 1.8896x; 1.1291x over previous
//
#include <hip/hip_runtime.h>

#define DI __device__ __forceinline__

typedef __attribute__((ext_vector_type(8))) short short8;
typedef __attribute__((ext_vector_type(4))) float f32x4;
typedef unsigned short u16;

// ---------- helpers ----------
DI u16 f2bf(float f) {
    union { float f; unsigned u; } v; v.f = f;
    unsigned u = v.u;
    return (u16)((u + 0x7fffu + ((u >> 16) & 1u)) >> 16);   // RNE
}
DI float bf2f(u16 h) {
    union { unsigned u; float f; } v; v.u = ((unsigned)h) << 16;
    return v.f;
}
// byte offset of 16B slot `slot` (0..3) of row `row` in a [rows][32]bf16 tile,
// XOR-swizzled: slot ^= (row>>1)&3 -> fragment reads/writes are 2-way (free).
DI int lds_off(int row, int slot) {
    return row * 64 + (((slot ^ ((row >> 1) & 3)) << 4));
}

// ---------- weight transpose+convert: Wt[N][K] bf16 = W[K][N] f32 ----------
// grid (K/32, ceil(N/32), L); 256 threads. dstL = per-layer dst stride (elems);
// caller pre-offsets Wt by the packed row offset.
__global__ __launch_bounds__(256) void k_wt(const float* __restrict__ W, u16* __restrict__ Wt,
                                            int K, int N, int dstL)
{
    __shared__ u16 t[32][33];
    const int tid = threadIdx.x;
    const int kt = blockIdx.x * 32, nt = blockIdx.y * 32;
    const float* Wl = W + (size_t)blockIdx.z * K * N;
    u16* Wtl = Wt + (size_t)blockIdx.z * dstL;
#pragma unroll
    for (int i = 0; i < 4; i++) {
        int k = kt + (tid >> 5) + i * 8;
        int n = nt + (tid & 31);
        float v = (n < N) ? Wl[(size_t)k * N + n] : 0.f;
        t[tid & 31][(tid >> 5) + i * 8] = f2bf(v);
    }
    __syncthreads();
#pragma unroll
    for (int i = 0; i < 4; i++) {
        int n = nt + (tid >> 5) + i * 8;
        int k = kt + (tid & 31);
        if (n < N) Wtl[(size_t)n * K + k] = t[(tid >> 5) + i * 8][tid & 31];
    }
}

// ---------- bias pack: dst[L][na+nb] = {a[L][na] | b[L][nb]} ----------
__global__ void k_packbias(const float* __restrict__ a, const float* __restrict__ b,
                           int na, int nb, float* __restrict__ dst)
{
    int i = blockIdx.x * 256 + threadIdx.x;
    int L = blockIdx.z;
    float* d = dst + (size_t)L * (na + nb);
    if (i < na) d[i] = a[(size_t)L * na + i];
    if (i < nb) d[na + i] = b[(size_t)L * nb + i];
}

// ---------- generic MFMA GEMM: C[M,N] = A[M,K] @ B[K,N] (+bias,+resid,relu) ----------
// TN=128, K-step 32. 256 threads = 4 waves (2x2); wave tile (TM/2) x 64.
// B pre-transposed bf16: Bt[N][K].
// AMODE: 0 = A f32; 1 = A f32 = A0+A1 (elementwise); 2 = A bf16 (TM=64 only)
// STORE: 0 = f32 linear ldc=N; 1 = bf16 "value layout" ((b*8+h)*8400+pix)*32+hd
template<int TM, int AMODE, int STORE, bool RELU, bool RESID>
__global__ __launch_bounds__(256) void k_gemm(
    const void* __restrict__ Ap, const float* __restrict__ A2,
    const u16* __restrict__ Bt, const float* __restrict__ bias,
    const float* __restrict__ resid, void* __restrict__ Cp,
    int M, int N, int K)
{
    constexpr int MI = TM / 32;
    __shared__ alignas(16) char Asm[TM * 64];    // TM rows x 32 bf16
    __shared__ alignas(16) char Bsm[128 * 64];   // 128 n-rows x 32 bf16
    const int tid  = threadIdx.x;
    const int lane = tid & 63;
    const int wave = tid >> 6;
    const int wr = wave >> 1, wc = wave & 1;
    const int m0 = blockIdx.x * TM, n0 = blockIdx.y * 128;

    f32x4 acc[MI][4] = {};

    for (int kb = 0; kb < K; kb += 32) {
        if (AMODE == 2) {
            const u16* A = (const u16*)Ap;
            int r = tid >> 2, ko = (tid & 3) << 3;
            int grow = m0 + r; if (grow > M - 1) grow = M - 1;
            uint4 v = *(const uint4*)(A + (size_t)grow * K + kb + ko);
            *(uint4*)(Asm + lds_off(r, ko >> 3)) = v;
        } else {
            constexpr int AIT = (TM * 8) / 256;
#pragma unroll
            for (int j = 0; j < AIT; j++) {
                int flat = tid + j * 256;
                int r = flat >> 3, kq = flat & 7;       // kq*4 = k offset
                int grow = m0 + r; if (grow > M - 1) grow = M - 1;
                const float* p = (const float*)Ap + (size_t)grow * K + kb + (kq << 2);
                float4 v = *(const float4*)p;
                if (AMODE == 1) {
                    float4 w = *(const float4*)(A2 + (size_t)grow * K + kb + (kq << 2));
                    v.x += w.x; v.y += w.y; v.z += w.z; v.w += w.w;
                }
                ushort4 h; h.x = f2bf(v.x); h.y = f2bf(v.y); h.z = f2bf(v.z); h.w = f2bf(v.w);
                *(ushort4*)(Asm + lds_off(r, kq >> 1) + ((kq & 1) << 3)) = h;
            }
        }
#pragma unroll
        for (int j = 0; j < 2; j++) {
            int item = tid + j * 256;               // 0..511
            int n = item >> 2, kq = item & 3;
            int gn = n0 + n; if (gn > N - 1) gn = N - 1;
            uint4 v = *(const uint4*)(Bt + (size_t)gn * K + kb + (kq << 3));
            *(uint4*)(Bsm + lds_off(n, kq)) = v;
        }
        __syncthreads();

        short8 af[MI], bfr[4];
#pragma unroll
        for (int mi = 0; mi < MI; mi++) {
            int r = wr * (TM / 2) + (mi << 4) + (lane & 15);
            af[mi] = *(const short8*)(Asm + lds_off(r, lane >> 4));
        }
#pragma unroll
        for (int ni = 0; ni < 4; ni++) {
            int c = (wc << 6) + (ni << 4) + (lane & 15);
            bfr[ni] = *(const short8*)(Bsm + lds_off(c, lane >> 4));
        }
#pragma unroll
        for (int mi = 0; mi < MI; mi++)
#pragma unroll
            for (int ni = 0; ni < 4; ni++)
                acc[mi][ni] = __builtin_amdgcn_mfma_f32_16x16x32_bf16(af[mi], bfr[ni], acc[mi][ni], 0, 0, 0);
        __syncthreads();
    }

    const int cl = lane & 15, rb = (lane >> 4) << 2;
#pragma unroll
    for (int mi = 0; mi < MI; mi++) {
#pragma unroll
        for (int ni = 0; ni < 4; ni++) {
            int col = n0 + (wc << 6) + (ni << 4) + cl;
            if (col >= N) continue;
            float bv = bias[col];
#pragma unroll
            for (int e = 0; e < 4; e++) {
                int row = m0 + wr * (TM / 2) + (mi << 4) + rb + e;
                if (row >= M) continue;
                float v = acc[mi][ni][e] + bv;
                if (RESID) v += resid[(size_t)row * N + col];
                if (RELU)  v = fmaxf(v, 0.f);
                if (STORE == 0) {
                    ((float*)Cp)[(size_t)row * N + col] = v;
                } else {
                    int b = row / 8400, pix = row - b * 8400;
                    int h = col >> 5, hd = col & 31;
                    ((u16*)Cp)[(((size_t)(b * 8 + h)) * 8400 + pix) * 32 + hd] = f2bf(v);
                }
            }
        }
    }
}

// ---------- MHA v2: block = (b,h,qtile of 75); thread = (q, channel-quarter) ----------
// qk buffer [4800][512]: Q at col h*32, K at col 256+h*32. V from ws_v [4800][256].
__global__ __launch_bounds__(320) void k_mha2(const float* __restrict__ qk, const float* __restrict__ Vp,
                                              float* __restrict__ outp)
{
    __shared__ float Ksh[300 * 32];   // 38.4 KB
    __shared__ u16   Vsh[300 * 32];   // 19.2 KB
    const int qt = blockIdx.x & 3;
    const int bh = blockIdx.x >> 2;
    const int h = bh & 7, b = bh >> 3;
    const float scale = 0.17677669529663687f;  // 1/sqrt(32)

    for (int i = threadIdx.x; i < 9600; i += 320) {
        int kk = i >> 5, dd = i & 31;
        size_t row = (size_t)(b * 300 + kk);
        Ksh[i] = qk[row * 512 + 256 + h * 32 + dd] * scale;
        Vsh[i] = f2bf(Vp[row * 256 + h * 32 + dd]);
    }
    __syncthreads();

    const int qq = threadIdx.x >> 2;       // 0..79 (75 active)
    const int quarter = threadIdx.x & 3;
    int q = qt * 75 + qq; if (q > 299) q = 299;
    const float* qg = qk + (size_t)(b * 300 + q) * 512 + h * 32 + quarter * 8;
    float qv[8];
    {
        float4 q0 = *(const float4*)qg, q1 = *(const float4*)(qg + 4);
        qv[0]=q0.x; qv[1]=q0.y; qv[2]=q0.z; qv[3]=q0.w;
        qv[4]=q1.x; qv[5]=q1.y; qv[6]=q1.z; qv[7]=q1.w;
    }

    float mx = -1e30f;
    for (int kk = 0; kk < 300; kk++) {
        const float* kr = Ksh + kk * 32 + quarter * 8;
        float4 k0 = *(const float4*)kr, k1 = *(const float4*)(kr + 4);
        float s = qv[0]*k0.x + qv[1]*k0.y + qv[2]*k0.z + qv[3]*k0.w
                + qv[4]*k1.x + qv[5]*k1.y + qv[6]*k1.z + qv[7]*k1.w;
        s += __shfl_xor(s, 1);
        s += __shfl_xor(s, 2);
        mx = fmaxf(mx, s);
    }
    float l = 0.f;
    float acc[8];
#pragma unroll
    for (int j = 0; j < 8; j++) acc[j] = 0.f;
    for (int kk = 0; kk < 300; kk++) {
        const float* kr = Ksh + kk * 32 + quarter * 8;
        float4 k0 = *(const float4*)kr, k1 = *(const float4*)(kr + 4);
        float s = qv[0]*k0.x + qv[1]*k0.y + qv[2]*k0.z + qv[3]*k0.w
                + qv[4]*k1.x + qv[5]*k1.y + qv[6]*k1.z + qv[7]*k1.w;
        s += __shfl_xor(s, 1);
        s += __shfl_xor(s, 2);
        float p = __expf(s - mx);
        l += p;
        uint4 vv = *(const uint4*)(Vsh + kk * 32 + quarter * 8);
        acc[0] += p * bf2f((u16)(vv.x & 0xffff));
        acc[1] += p * bf2f((u16)(vv.x >> 16));
        acc[2] += p * bf2f((u16)(vv.y & 0xffff));
        acc[3] += p * bf2f((u16)(vv.y >> 16));
        acc[4] += p * bf2f((u16)(vv.z & 0xffff));
        acc[5] += p * bf2f((u16)(vv.z >> 16));
        acc[6] += p * bf2f((u16)(vv.w & 0xffff));
        acc[7] += p * bf2f((u16)(vv.w >> 16));
    }
    if (qq < 75) {
        float inv = 1.f / l;
        float* op = outp + (size_t)(b * 300 + qt * 75 + qq) * 256 + h * 32 + quarter * 8;
        float4 o0, o1;
        o0.x = acc[0]*inv; o0.y = acc[1]*inv; o0.z = acc[2]*inv; o0.w = acc[3]*inv;
        o1.x = acc[4]*inv; o1.y = acc[5]*inv; o1.z = acc[6]*inv; o1.w = acc[7]*inv;
        *(float4*)op = o0;
        *(float4*)(op + 4) = o1;
    }
}

// ---------- LayerNorm: one wave per row of 256 ----------
__global__ __launch_bounds__(256) void k_ln(const float* __restrict__ x, const float* __restrict__ g,
                                            const float* __restrict__ bb, float* __restrict__ out, int M)
{
    int row = blockIdx.x * 4 + (threadIdx.x >> 6);
    int lane = threadIdx.x & 63;
    if (row >= M) return;
    const float* xr = x + (size_t)row * 256;
    float4 v = *(const float4*)(xr + lane * 4);
    float s  = v.x + v.y + v.z + v.w;
    float s2 = v.x*v.x + v.y*v.y + v.z*v.z + v.w*v.w;
#pragma unroll
    for (int off = 32; off >= 1; off >>= 1) {
        s  += __shfl_xor(s, off);
        s2 += __shfl_xor(s2, off);
    }
    float m   = s * 0.00390625f;
    float var = s2 * 0.00390625f - m * m;
    float r   = rsqrtf(var + 1e-5f);
    float4 gv = *(const float4*)(g + lane * 4);
    float4 bv = *(const float4*)(bb + lane * 4);
    float4 o;
    o.x = (v.x - m) * r * gv.x + bv.x;
    o.y = (v.y - m) * r * gv.y + bv.y;
    o.z = (v.z - m) * r * gv.z + bv.z;
    o.w = (v.w - m) * r * gv.w + bv.w;
    *(float4*)(out + (size_t)row * 256 + lane * 4) = o;
}

// ---------- aw softmax over 12 per (b,q,h), inside fused offaw [4800][288] ----------
__global__ void k_awsm(float* __restrict__ offaw, int n)
{
    int g = blockIdx.x * 256 + threadIdx.x;
    if (g >= n) return;
    int row = g >> 3, h = g & 7;
    float* p = offaw + (size_t)row * 288 + 192 + h * 12;
    float m = p[0];
#pragma unroll
    for (int i = 1; i < 12; i++) m = fmaxf(m, p[i]);
    float e[12]; float s = 0.f;
#pragma unroll
    for (int i = 0; i < 12; i++) { e[i] = __expf(p[i] - m); s += e[i]; }
    float inv = 1.f / s;
#pragma unroll
    for (int i = 0; i < 12; i++) p[i] = e[i] * inv;
}

// ---------- deformable sampling: lane = channel (32/item), 8 items/block ----------
__global__ __launch_bounds__(256) void k_msda(const u16* __restrict__ value, const float* __restrict__ offaw,
                                              const float* __restrict__ ref, float* __restrict__ samp)
{
    int it = blockIdx.x * 8 + (threadIdx.x >> 5);
    int d  = threadIdx.x & 31;
    int h = it & 7, row = it >> 3;
    int b = row / 300;
    const float* rf = ref + (size_t)row * 4;
    float rx = rf[0], ry = rf[1];
    float rw = rf[2] * 0.125f, rh = rf[3] * 0.125f;   // /P * 0.5
    const float* offp = offaw + (size_t)row * 288 + h * 24;
    const float* awp  = offaw + (size_t)row * 288 + 192 + h * 12;
    const u16* vb = value + ((size_t)(b * 8 + h)) * 8400 * 32 + d;
    const int HW[3] = {80, 40, 20};
    const int st[3] = {0, 6400, 8000};
    float acc = 0.f;
#pragma unroll
    for (int lv = 0; lv < 3; lv++) {
        int Wl = HW[lv], Hl = HW[lv];
        float Wf = (float)Wl, Hf = (float)Hl;
#pragma unroll
        for (int p = 0; p < 4; p++) {
            float a = awp[lv * 4 + p];
            float x = (rx + offp[lv*8 + p*2]     * rw) * Wf - 0.5f;
            float y = (ry + offp[lv*8 + p*2 + 1] * rh) * Hf - 0.5f;
            float xf = floorf(x), yf = floorf(y);
            float wx = x - xf, wy = y - yf;
            int x0 = (int)xf, y0 = (int)yf;
#pragma unroll
            for (int t = 0; t < 4; t++) {
                int xx = x0 + (t & 1), yy = y0 + (t >> 1);
                if (xx >= 0 && xx < Wl && yy >= 0 && yy < Hl) {
                    float w = ((t & 1) ? wx : 1.f - wx) * ((t >> 1) ? wy : 1.f - wy);
                    acc += a * w * bf2f(vb[(size_t)(st[lv] + yy * Wl + xx) * 32]);
                }
            }
        }
    }
    samp[(size_t)row * 256 + h * 32 + d] = acc;
}

// ---------- qpe hidden: relu(ref(4) @ W1(4,512) + b1) ----------
__global__ void k_qpe_hidden(const float* __restrict__ ref, const float* __restrict__ W1,
                             const float* __restrict__ b1, float* __restrict__ hid)
{
    int idx = blockIdx.x * 256 + threadIdx.x;
    if (idx >= 4800 * 512) return;
    int row = idx >> 9, col = idx & 511;
    const float* r = ref + (size_t)row * 4;
    float v = b1[col] + r[0]*W1[col] + r[1]*W1[512+col] + r[2]*W1[1024+col] + r[3]*W1[1536+col];
    hid[idx] = fmaxf(v, 0.f);
}

// ---------- bbox tail ----------
__global__ __launch_bounds__(64) void k_bb3(const float* __restrict__ bb2, const float* __restrict__ W3,
                                            const float* __restrict__ b3, float* __restrict__ ref)
{
    int row = blockIdx.x;
    int lane = threadIdx.x;
    const float* xr = bb2 + (size_t)row * 256;
    float s0 = 0, s1 = 0, s2 = 0, s3 = 0;
#pragma unroll
    for (int k = lane; k < 256; k += 64) {
        float xv = xr[k];
        float4 w = *(const float4*)(W3 + k * 4);
        s0 += xv * w.x; s1 += xv * w.y; s2 += xv * w.z; s3 += xv * w.w;
    }
#pragma unroll
    for (int off = 32; off >= 1; off >>= 1) {
        s0 += __shfl_xor(s0, off); s1 += __shfl_xor(s1, off);
        s2 += __shfl_xor(s2, off); s3 += __shfl_xor(s3, off);
    }
    if (lane == 0) {
        float sv[4] = {s0, s1, s2, s3};
        float* rr = ref + (size_t)row * 4;
#pragma unroll
        for (int j = 0; j < 4; j++) {
            float v = sv[j] + b3[j];
            float o = rr[j];
            o = fminf(fmaxf(o, 1e-5f), 1.f - 1e-5f);
            float inv = logf(o / (1.f - o));
            rr[j] = 1.f / (1.f + expf(-(v + inv)));
        }
    }
}

// ---------- small utility kernels ----------
__global__ void k_cvt_bf16(const float* __restrict__ in, u16* __restrict__ out, int n4)
{
    int i = blockIdx.x * 256 + threadIdx.x;
    if (i >= n4) return;
    float4 v = ((const float4*)in)[i];
    ushort4 h; h.x = f2bf(v.x); h.y = f2bf(v.y); h.z = f2bf(v.z); h.w = f2bf(v.w);
    ((ushort4*)out)[i] = h;
}
__global__ void k_copy4(const float* __restrict__ in, float* __restrict__ out, int n4)
{
    int i = blockIdx.x * 256 + threadIdx.x;
    if (i >= n4) return;
    ((float4*)out)[i] = ((const float4*)in)[i];
}
__global__ void k_sigmoid(const float* __restrict__ in, float* __restrict__ out, int n)
{
    int i = blockIdx.x * 256 + threadIdx.x;
    if (i >= n) return;
    out[i] = 1.f / (1.f + __expf(-in[i]));
}

// ---------- host-side launch helpers ----------
static inline dim3 g32(int M, int N) { return dim3((M + 31) / 32, (N + 127) / 128); }

static void gemm_plain(const float* A, const u16* Bt, const float* bias, float* C,
                       int M, int N, int K, hipStream_t s) {
    k_gemm<32, 0, 0, false, false><<<g32(M, N), 256, 0, s>>>((const void*)A, nullptr, Bt, bias, nullptr, (void*)C, M, N, K);
}
static void gemm_add(const float* A, const float* A2, const u16* Bt, const float* bias, float* C,
                     int M, int N, int K, hipStream_t s) {
    k_gemm<32, 1, 0, false, false><<<g32(M, N), 256, 0, s>>>((const void*)A, A2, Bt, bias, nullptr, (void*)C, M, N, K);
}
static void gemm_resid(const float* A, const u16* Bt, const float* bias, const float* resid, float* C,
                       int M, int N, int K, hipStream_t s) {
    k_gemm<32, 0, 0, false, true><<<g32(M, N), 256, 0, s>>>((const void*)A, nullptr, Bt, bias, resid, (void*)C, M, N, K);
}
static void gemm_relu(const float* A, const u16* Bt, const float* bias, float* C,
                      int M, int N, int K, hipStream_t s) {
    k_gemm<32, 0, 0, true, false><<<g32(M, N), 256, 0, s>>>((const void*)A, nullptr, Bt, bias, nullptr, (void*)C, M, N, K);
}
static void gemm_value(const u16* A, const u16* Bt, const float* bias, u16* C, hipStream_t s) {
    k_gemm<64, 2, 1, false, false><<<dim3(2100, 2), 256, 0, s>>>((const void*)A, nullptr, Bt, bias, nullptr, (void*)C, 134400, 256, 256);
}

extern "C" void kernel_launch(void* const* d_in, const int* in_sizes, int n_in,
                              void* d_out, int out_size, void* d_ws, size_t ws_size,
                              hipStream_t stream)
{
    const float* tgt       = (const float*)d_in[0];
    const float* ref_unact = (const float*)d_in[1];
    const float* memory    = (const float*)d_in[2];
    const float* self_Wq = (const float*)d_in[4];
    const float* self_bq = (const float*)d_in[5];
    const float* self_Wk = (const float*)d_in[6];
    const float* self_bk = (const float*)d_in[7];
    const float* self_Wv = (const float*)d_in[8];
    const float* self_bv = (const float*)d_in[9];
    const float* self_Wo = (const float*)d_in[10];
    const float* self_bo = (const float*)d_in[11];
    const float* ln1_g = (const float*)d_in[12];
    const float* ln1_b = (const float*)d_in[13];
    const float* ln2_g = (const float*)d_in[14];
    const float* ln2_b = (const float*)d_in[15];
    const float* ln3_g = (const float*)d_in[16];
    const float* ln3_b = (const float*)d_in[17];
    const float* off_W = (const float*)d_in[18];
    const float* off_b = (const float*)d_in[19];
    const float* aw_W  = (const float*)d_in[20];
    const float* aw_b  = (const float*)d_in[21];
    const float* val_W = (const float*)d_in[22];
    const float* val_b = (const float*)d_in[23];
    const float* out_W = (const float*)d_in[24];
    const float* out_b = (const float*)d_in[25];
    const float* ffn_W1 = (const float*)d_in[26];
    const float* ffn_b1 = (const float*)d_in[27];
    const float* ffn_W2 = (const float*)d_in[28];
    const float* ffn_b2 = (const float*)d_in[29];
    const float* qph_W1 = (const float*)d_in[30];
    const float* qph_b1 = (const float*)d_in[31];
    const float* qph_W2 = (const float*)d_in[32];
    const float* qph_b2 = (const float*)d_in[33];
    const float* bb_W1 = (const float*)d_in[34];
    const float* bb_b1 = (const float*)d_in[35];
    const float* bb_W2 = (const float*)d_in[36];
    const float* bb_b2 = (const float*)d_in[37];
    const float* bb_W3 = (const float*)d_in[38];
    const float* bb_b3 = (const float*)d_in[39];
    const float* sc_W  = (const float*)d_in[40];
    const float* sc_b  = (const float*)d_in[41];
    float* out_f = (float*)d_out;

    // ---- workspace layout (bytes) ----
    char* w = (char*)d_ws;
    u16* mem_bf = (u16*)(w + 0);                // 68,812,800 B
    u16* value  = (u16*)(w + 68812800);         // 68,812,800 B
    const size_t F0 = 137625600;
    float* ws_out   = (float*)(w + F0);
    float* ws_tmp   = (float*)(w + F0 +  4915200);
    float* ws_qpe   = (float*)(w + F0 +  9830400);
    float* ws_hid   = (float*)(w + F0 + 14745600);  // 4800x512
    float* ws_qk    = (float*)(w + F0 + 24576000);  // 4800x512 (Q | K)
    float* ws_v     = (float*)(w + F0 + 34406400);
    float* ws_attn  = (float*)(w + F0 + 39321600);
    float* ws_offaw = (float*)(w + F0 + 44236800);  // 4800x288 (off | aw)
    float* ws_samp  = (float*)(w + F0 + 49766400);
    float* ws_ffn   = (float*)(w + F0 + 54681600);  // 4800x1024
    float* ws_bb1   = (float*)(w + F0 + 74342400);
    float* ws_bb2   = (float*)(w + F0 + 79257600);
    float* ws_ref   = (float*)(w + F0 + 84172800);  // 4800x4
    float* bias_qk  = (float*)(w + F0 + 84256800);  // 6 x 512
    float* bias_oa  = (float*)(w + F0 + 84269088);  // 6 x 288
    // ---- bf16 transposed weights (u16 elements), 16B-aligned ----
    u16* wt = (u16*)(w + F0 + 84276000);
    u16* wt_qk    = wt;                    // 6 x 512x256
    u16* wt_v     = wt_qk    + 786432;     // 6 x 65536
    u16* wt_o     = wt_v     + 393216;
    u16* wt_offaw = wt_o     + 393216;     // 6 x 288x256
    u16* wt_val   = wt_offaw + 442368;
    u16* wt_out   = wt_val   + 393216;
    u16* wt_f1    = wt_out   + 393216;     // 6 x 262144
    u16* wt_f2    = wt_f1    + 1572864;
    u16* wt_b1    = wt_f2    + 1572864;
    u16* wt_b2    = wt_b1    + 393216;
    u16* wt_qp2   = wt_b2    + 393216;     // 131072
    u16* wt_sc    = wt_qp2   + 131072;     // 20480

    // ---- init: weight transposes + bias packs ----
    k_wt<<<dim3(8, 8, 6),  256, 0, stream>>>(self_Wq, wt_qk,            256, 256, 131072);
    k_wt<<<dim3(8, 8, 6),  256, 0, stream>>>(self_Wk, wt_qk + 65536,    256, 256, 131072);
    k_wt<<<dim3(8, 8, 6),  256, 0, stream>>>(self_Wv, wt_v,             256, 256, 65536);
    k_wt<<<dim3(8, 8, 6),  256, 0, stream>>>(self_Wo, wt_o,             256, 256, 65536);
    k_wt<<<dim3(8, 6, 6),  256, 0, stream>>>(off_W,   wt_offaw,         256, 192, 73728);
    k_wt<<<dim3(8, 3, 6),  256, 0, stream>>>(aw_W,    wt_offaw + 49152, 256, 96,  73728);
    k_wt<<<dim3(8, 8, 6),  256, 0, stream>>>(val_W,   wt_val,           256, 256, 65536);
    k_wt<<<dim3(8, 8, 6),  256, 0, stream>>>(out_W,   wt_out,           256, 256, 65536);
    k_wt<<<dim3(8, 32, 6), 256, 0, stream>>>(ffn_W1,  wt_f1,            256, 1024, 262144);
    k_wt<<<dim3(32, 8, 6), 256, 0, stream>>>(ffn_W2,  wt_f2,            1024, 256, 262144);
    k_wt<<<dim3(8, 8, 6),  256, 0, stream>>>(bb_W1,   wt_b1,            256, 256, 65536);
    k_wt<<<dim3(8, 8, 6),  256, 0, stream>>>(bb_W2,   wt_b2,            256, 256, 65536);
    k_wt<<<dim3(16, 8, 1), 256, 0, stream>>>(qph_W2,  wt_qp2,           512, 256, 131072);
    k_wt<<<dim3(8, 3, 1),  256, 0, stream>>>(sc_W + (size_t)5 * 20480, wt_sc, 256, 80, 20480);
    k_packbias<<<dim3(1, 1, 6), 256, 0, stream>>>(self_bq, self_bk, 256, 256, bias_qk);
    k_packbias<<<dim3(1, 1, 6), 256, 0, stream>>>(off_b, aw_b, 192, 96, bias_oa);

    k_cvt_bf16<<<33600, 256, 0, stream>>>(memory, mem_bf, 8601600);
    k_copy4   <<<1200,  256, 0, stream>>>(tgt, ws_out, 307200);
    k_sigmoid <<<75,    256, 0, stream>>>(ref_unact, ws_ref, 19200);

    for (int l = 0; l < 6; l++) {
        // qpe = relu(ref @ qph_W1 + b1) @ qph_W2 + b2
        k_qpe_hidden<<<9600, 256, 0, stream>>>(ws_ref, qph_W1, qph_b1, ws_hid);
        gemm_plain(ws_hid, wt_qp2, qph_b2, ws_qpe, 4800, 256, 512, stream);

        // self-attention (fused Q|K projection)
        gemm_add(ws_out, ws_qpe, wt_qk + (size_t)l * 131072, bias_qk + l * 512, ws_qk, 4800, 512, 256, stream);
        gemm_plain(ws_out, wt_v + (size_t)l * 65536, self_bv + l * 256, ws_v, 4800, 256, 256, stream);
        k_mha2<<<512, 320, 0, stream>>>(ws_qk, ws_v, ws_attn);
        gemm_resid(ws_attn, wt_o + (size_t)l * 65536, self_bo + l * 256, ws_out, ws_tmp, 4800, 256, 256, stream);
        k_ln<<<1200, 256, 0, stream>>>(ws_tmp, ln1_g + l * 256, ln1_b + l * 256, ws_out, 4800);

        // value projection (bf16 A, bf16 out, (b,h,pix,hd) layout)
        gemm_value(mem_bf, wt_val + (size_t)l * 65536, val_b + l * 256, value, stream);

        // deformable attention (fused off|aw projection)
        gemm_add(ws_out, ws_qpe, wt_offaw + (size_t)l * 73728, bias_oa + l * 288, ws_offaw, 4800, 288, 256, stream);
        k_awsm<<<150, 256, 0, stream>>>(ws_offaw, 38400);
        k_msda<<<4800, 256, 0, stream>>>(value, ws_offaw, ws_ref, ws_samp);
        gemm_resid(ws_samp, wt_out + (size_t)l * 65536, out_b + l * 256, ws_out, ws_tmp, 4800, 256, 256, stream);
        k_ln<<<1200, 256, 0, stream>>>(ws_tmp, ln2_g + l * 256, ln2_b + l * 256, ws_out, 4800);

        // FFN
        gemm_relu(ws_out, wt_f1 + (size_t)l * 262144, ffn_b1 + l * 1024, ws_ffn, 4800, 1024, 256, stream);
        gemm_resid(ws_ffn, wt_f2 + (size_t)l * 262144, ffn_b2 + l * 256, ws_out, ws_tmp, 4800, 256, 1024, stream);
        k_ln<<<1200, 256, 0, stream>>>(ws_tmp, ln3_g + l * 256, ln3_b + l * 256, ws_out, 4800);

        // bbox head + ref update
        gemm_relu(ws_out, wt_b1 + (size_t)l * 65536, bb_b1 + l * 256, ws_bb1, 4800, 256, 256, stream);
        gemm_relu(ws_bb1, wt_b2 + (size_t)l * 65536, bb_b2 + l * 256, ws_bb2, 4800, 256, 256, stream);
        k_bb3<<<4800, 64, 0, stream>>>(ws_bb2, bb_W3 + (size_t)l * 1024, bb_b3 + l * 4, ws_ref);
    }

    // outputs: ref (19200 f32) then logits (4800x80 f32)
    k_copy4<<<19, 256, 0, stream>>>(ws_ref, out_f, 4800);
    gemm_plain(ws_out, wt_sc, sc_b + 5 * 80, out_f + 19200, 4800, 80, 256, stream);
}

// Round 7
// 2207.504 us; speedup vs baseline: 2.3393x; 1.2380x over previous
//
#include <hip/hip_runtime.h>

#define DI __device__ __forceinline__

typedef __attribute__((ext_vector_type(8))) short short8;
typedef __attribute__((ext_vector_type(4))) float f32x4;
typedef unsigned short u16;

// ---------- helpers ----------
DI u16 f2bf(float f) {
    union { float f; unsigned u; } v; v.f = f;
    unsigned u = v.u;
    return (u16)((u + 0x7fffu + ((u >> 16) & 1u)) >> 16);   // RNE
}
DI float bf2f(u16 h) {
    union { unsigned u; float f; } v; v.u = ((unsigned)h) << 16;
    return v.f;
}
// byte offset of 16B slot `slot` (0..3) of row `row` in a [rows][32]bf16 tile,
// XOR-swizzled: slot ^= (row>>1)&3 -> fragment reads/writes are 2-way (free).
DI int lds_off(int row, int slot) {
    return row * 64 + (((slot ^ ((row >> 1) & 3)) << 4));
}

// ---------- weight transpose+convert: Wt[N][K] bf16 = W[K][N] f32 ----------
__global__ __launch_bounds__(256) void k_wt(const float* __restrict__ W, u16* __restrict__ Wt,
                                            int K, int N, int dstL)
{
    __shared__ u16 t[32][33];
    const int tid = threadIdx.x;
    const int kt = blockIdx.x * 32, nt = blockIdx.y * 32;
    const float* Wl = W + (size_t)blockIdx.z * K * N;
    u16* Wtl = Wt + (size_t)blockIdx.z * dstL;
#pragma unroll
    for (int i = 0; i < 4; i++) {
        int k = kt + (tid >> 5) + i * 8;
        int n = nt + (tid & 31);
        float v = (n < N) ? Wl[(size_t)k * N + n] : 0.f;
        t[tid & 31][(tid >> 5) + i * 8] = f2bf(v);
    }
    __syncthreads();
#pragma unroll
    for (int i = 0; i < 4; i++) {
        int n = nt + (tid >> 5) + i * 8;
        int k = kt + (tid & 31);
        if (n < N) Wtl[(size_t)n * K + k] = t[(tid >> 5) + i * 8][tid & 31];
    }
}

// ---------- bias pack: dst[L][na+nb] = {a[L][na] | b[L][nb]} ----------
__global__ void k_packbias(const float* __restrict__ a, const float* __restrict__ b,
                           int na, int nb, float* __restrict__ dst)
{
    int i = blockIdx.x * 256 + threadIdx.x;
    int L = blockIdx.z;
    float* d = dst + (size_t)L * (na + nb);
    if (i < na) d[i] = a[(size_t)L * na + i];
    if (i < nb) d[na + i] = b[(size_t)L * nb + i];
}

// ---------- generic MFMA GEMM ----------
template<int TM, int AMODE, int STORE, bool RELU, bool RESID>
__global__ __launch_bounds__(256) void k_gemm(
    const void* __restrict__ Ap, const float* __restrict__ A2,
    const u16* __restrict__ Bt, const float* __restrict__ bias,
    const float* __restrict__ resid, void* __restrict__ Cp,
    int M, int N, int K)
{
    constexpr int MI = TM / 32;
    __shared__ alignas(16) char Asm[TM * 64];    // TM rows x 32 bf16
    __shared__ alignas(16) char Bsm[128 * 64];   // 128 n-rows x 32 bf16
    const int tid  = threadIdx.x;
    const int lane = tid & 63;
    const int wave = tid >> 6;
    const int wr = wave >> 1, wc = wave & 1;
    const int m0 = blockIdx.x * TM, n0 = blockIdx.y * 128;

    f32x4 acc[MI][4] = {};

    for (int kb = 0; kb < K; kb += 32) {
        if (AMODE == 2) {
            const u16* A = (const u16*)Ap;
            int r = tid >> 2, ko = (tid & 3) << 3;
            int grow = m0 + r; if (grow > M - 1) grow = M - 1;
            uint4 v = *(const uint4*)(A + (size_t)grow * K + kb + ko);
            *(uint4*)(Asm + lds_off(r, ko >> 3)) = v;
        } else {
            constexpr int AIT = (TM * 8) / 256;
#pragma unroll
            for (int j = 0; j < AIT; j++) {
                int flat = tid + j * 256;
                int r = flat >> 3, kq = flat & 7;       // kq*4 = k offset
                int grow = m0 + r; if (grow > M - 1) grow = M - 1;
                const float* p = (const float*)Ap + (size_t)grow * K + kb + (kq << 2);
                float4 v = *(const float4*)p;
                if (AMODE == 1) {
                    float4 w = *(const float4*)(A2 + (size_t)grow * K + kb + (kq << 2));
                    v.x += w.x; v.y += w.y; v.z += w.z; v.w += w.w;
                }
                ushort4 h; h.x = f2bf(v.x); h.y = f2bf(v.y); h.z = f2bf(v.z); h.w = f2bf(v.w);
                *(ushort4*)(Asm + lds_off(r, kq >> 1) + ((kq & 1) << 3)) = h;
            }
        }
#pragma unroll
        for (int j = 0; j < 2; j++) {
            int item = tid + j * 256;               // 0..511
            int n = item >> 2, kq = item & 3;
            int gn = n0 + n; if (gn > N - 1) gn = N - 1;
            uint4 v = *(const uint4*)(Bt + (size_t)gn * K + kb + (kq << 3));
            *(uint4*)(Bsm + lds_off(n, kq)) = v;
        }
        __syncthreads();

        short8 af[MI], bfr[4];
#pragma unroll
        for (int mi = 0; mi < MI; mi++) {
            int r = wr * (TM / 2) + (mi << 4) + (lane & 15);
            af[mi] = *(const short8*)(Asm + lds_off(r, lane >> 4));
        }
#pragma unroll
        for (int ni = 0; ni < 4; ni++) {
            int c = (wc << 6) + (ni << 4) + (lane & 15);
            bfr[ni] = *(const short8*)(Bsm + lds_off(c, lane >> 4));
        }
#pragma unroll
        for (int mi = 0; mi < MI; mi++)
#pragma unroll
            for (int ni = 0; ni < 4; ni++)
                acc[mi][ni] = __builtin_amdgcn_mfma_f32_16x16x32_bf16(af[mi], bfr[ni], acc[mi][ni], 0, 0, 0);
        __syncthreads();
    }

    const int cl = lane & 15, rb = (lane >> 4) << 2;
#pragma unroll
    for (int mi = 0; mi < MI; mi++) {
#pragma unroll
        for (int ni = 0; ni < 4; ni++) {
            int col = n0 + (wc << 6) + (ni << 4) + cl;
            if (col >= N) continue;
            float bv = bias[col];
#pragma unroll
            for (int e = 0; e < 4; e++) {
                int row = m0 + wr * (TM / 2) + (mi << 4) + rb + e;
                if (row >= M) continue;
                float v = acc[mi][ni][e] + bv;
                if (RESID) v += resid[(size_t)row * N + col];
                if (RELU)  v = fmaxf(v, 0.f);
                if (STORE == 0) {
                    ((float*)Cp)[(size_t)row * N + col] = v;
                } else {
                    int b = row / 8400, pix = row - b * 8400;
                    int h = col >> 5, hd = col & 31;
                    ((u16*)Cp)[(((size_t)(b * 8 + h)) * 8400 + pix) * 32 + hd] = f2bf(v);
                }
            }
        }
    }
}

// ---------- MHA v3: MFMA flash attention ----------
// grid (5 qtiles of 64, 128 bh); 256 thr = 4 waves; wave owns 16 q rows.
// qk [4800][512] (Q cols h*32, K cols 256+h*32); V [4800][256]; out [4800][256].
// LDS union: P[64][328]bf16 (aliases K[304][40]bf16) + Vt[32][328]bf16 = 62976 B.
__global__ __launch_bounds__(256) void k_mha3(const float* __restrict__ qk, const float* __restrict__ Vp,
                                              float* __restrict__ outp)
{
    __shared__ alignas(16) char lds[62976];
    u16* Ksh = (u16*)lds;              // [304][40] (k rows, d cols), dead after QK
    u16* Psh = (u16*)lds;              // [64][328]  (q rows, k cols), aliases Ksh
    u16* Vt  = (u16*)(lds + 41984);    // [32][328]  (d rows, k cols)

    const int q0 = blockIdx.x * 64;
    const int bh = blockIdx.y;
    const int h = bh & 7, b = bh >> 3;
    const int tid = threadIdx.x;
    const int wv = tid >> 6, l = tid & 63;
    const int c15 = l & 15, slot = l >> 4;
    const float scale = 0.17677669529663687f;  // 1/sqrt(32)

    // ---- stage K [304 rows][32 d] bf16 (rows>=300 zero) ----
    for (int item = tid; item < 304 * 8; item += 256) {
        int kk = item >> 3, dq = (item & 7) << 2;
        ushort4 hv = {0, 0, 0, 0};
        if (kk < 300) {
            float4 v = *(const float4*)(qk + (size_t)(b * 300 + kk) * 512 + 256 + h * 32 + dq);
            hv.x = f2bf(v.x); hv.y = f2bf(v.y); hv.z = f2bf(v.z); hv.w = f2bf(v.w);
        }
        *(ushort4*)(Ksh + kk * 40 + dq) = hv;
    }
    // ---- stage V transposed: Vt[d][k], k in [0,320) (k>=300 zero) ----
    for (int item = tid; item < 320 * 8; item += 256) {
        int kk = item >> 3, dq = (item & 7) << 2;
        float4 v = {0, 0, 0, 0};
        if (kk < 300)
            v = *(const float4*)(Vp + (size_t)(b * 300 + kk) * 256 + h * 32 + dq);
        Vt[(dq + 0) * 328 + kk] = f2bf(v.x);
        Vt[(dq + 1) * 328 + kk] = f2bf(v.y);
        Vt[(dq + 2) * 328 + kk] = f2bf(v.z);
        Vt[(dq + 3) * 328 + kk] = f2bf(v.w);
    }
    // ---- Q A-fragment from global (scaled) ----
    short8 qf;
    {
        int qrow = q0 + 16 * wv + c15; if (qrow > 299) qrow = 299;
        const float* qs = qk + (size_t)(b * 300 + qrow) * 512 + h * 32 + (slot << 3);
        float4 a0 = *(const float4*)qs, a1 = *(const float4*)(qs + 4);
        qf[0] = (short)f2bf(a0.x * scale); qf[1] = (short)f2bf(a0.y * scale);
        qf[2] = (short)f2bf(a0.z * scale); qf[3] = (short)f2bf(a0.w * scale);
        qf[4] = (short)f2bf(a1.x * scale); qf[5] = (short)f2bf(a1.y * scale);
        qf[6] = (short)f2bf(a1.z * scale); qf[7] = (short)f2bf(a1.w * scale);
    }
    __syncthreads();

    // ---- QK^T: 19 k-tiles of 16, scores in registers ----
    f32x4 sc[19];
    const f32x4 zero4 = {0.f, 0.f, 0.f, 0.f};
#pragma unroll
    for (int t = 0; t < 19; t++) {
        short8 kf = *(const short8*)(Ksh + (16 * t + c15) * 40 + (slot << 3));
        sc[t] = __builtin_amdgcn_mfma_f32_16x16x32_bf16(qf, kf, zero4, 0, 0, 0);
    }
    __syncthreads();   // K dead everywhere; P may now overwrite it

    // ---- in-register softmax; P -> LDS bf16 ----
    // lane holds: q row (local) = 16*wv + slot*4 + e ; k col = 16*t + c15
    float linv[4];
    const int prow0 = 16 * wv + (slot << 2);
#pragma unroll
    for (int e = 0; e < 4; e++) {
        float mm = -1e30f;
#pragma unroll
        for (int t = 0; t < 18; t++) mm = fmaxf(mm, sc[t][e]);
        if (c15 < 12) mm = fmaxf(mm, sc[18][e]);
        mm = fmaxf(mm, __shfl_xor(mm, 1));
        mm = fmaxf(mm, __shfl_xor(mm, 2));
        mm = fmaxf(mm, __shfl_xor(mm, 4));
        mm = fmaxf(mm, __shfl_xor(mm, 8));
        float ls = 0.f;
#pragma unroll
        for (int t = 0; t < 19; t++) {
            float p = __expf(sc[t][e] - mm);
            if (t == 18 && c15 >= 12) p = 0.f;
            ls += p;
            Psh[(prow0 + e) * 328 + 16 * t + c15] = f2bf(p);
        }
        ls += __shfl_xor(ls, 1);
        ls += __shfl_xor(ls, 2);
        ls += __shfl_xor(ls, 4);
        ls += __shfl_xor(ls, 8);
        linv[e] = 1.f / ls;
    }
    // zero P cols 304..319 of this wave's rows (PV k-steps reach 319)
    {
        int r = 16 * wv + (l >> 2);
        int c = 304 + ((l & 3) << 2);
        Psh[r * 328 + c + 0] = 0; Psh[r * 328 + c + 1] = 0;
        Psh[r * 328 + c + 2] = 0; Psh[r * 328 + c + 3] = 0;
    }
    // (P written/read by same wave only; LDS ops are in-order per wave)

    // ---- PV: O[16q x 32d] per wave, 10 k-steps of 32 ----
#pragma unroll
    for (int df = 0; df < 2; df++) {
        f32x4 o = zero4;
#pragma unroll
        for (int t = 0; t < 10; t++) {
            short8 pf = *(const short8*)(Psh + (16 * wv + c15) * 328 + 32 * t + (slot << 3));
            short8 vf = *(const short8*)(Vt + (16 * df + c15) * 328 + 32 * t + (slot << 3));
            o = __builtin_amdgcn_mfma_f32_16x16x32_bf16(pf, vf, o, 0, 0, 0);
        }
#pragma unroll
        for (int e = 0; e < 4; e++) {
            int qrow = q0 + prow0 + e;
            if (qrow < 300)
                outp[(size_t)(b * 300 + qrow) * 256 + h * 32 + 16 * df + c15] = o[e] * linv[e];
        }
    }
}

// ---------- LayerNorm: one wave per row of 256 ----------
__global__ __launch_bounds__(256) void k_ln(const float* __restrict__ x, const float* __restrict__ g,
                                            const float* __restrict__ bb, float* __restrict__ out, int M)
{
    int row = blockIdx.x * 4 + (threadIdx.x >> 6);
    int lane = threadIdx.x & 63;
    if (row >= M) return;
    const float* xr = x + (size_t)row * 256;
    float4 v = *(const float4*)(xr + lane * 4);
    float s  = v.x + v.y + v.z + v.w;
    float s2 = v.x*v.x + v.y*v.y + v.z*v.z + v.w*v.w;
#pragma unroll
    for (int off = 32; off >= 1; off >>= 1) {
        s  += __shfl_xor(s, off);
        s2 += __shfl_xor(s2, off);
    }
    float m   = s * 0.00390625f;
    float var = s2 * 0.00390625f - m * m;
    float r   = rsqrtf(var + 1e-5f);
    float4 gv = *(const float4*)(g + lane * 4);
    float4 bv = *(const float4*)(bb + lane * 4);
    float4 o;
    o.x = (v.x - m) * r * gv.x + bv.x;
    o.y = (v.y - m) * r * gv.y + bv.y;
    o.z = (v.z - m) * r * gv.z + bv.z;
    o.w = (v.w - m) * r * gv.w + bv.w;
    *(float4*)(out + (size_t)row * 256 + lane * 4) = o;
}

// ---------- aw softmax over 12 per (b,q,h), inside fused offaw [4800][288] ----------
__global__ void k_awsm(float* __restrict__ offaw, int n)
{
    int g = blockIdx.x * 256 + threadIdx.x;
    if (g >= n) return;
    int row = g >> 3, h = g & 7;
    float* p = offaw + (size_t)row * 288 + 192 + h * 12;
    float m = p[0];
#pragma unroll
    for (int i = 1; i < 12; i++) m = fmaxf(m, p[i]);
    float e[12]; float s = 0.f;
#pragma unroll
    for (int i = 0; i < 12; i++) { e[i] = __expf(p[i] - m); s += e[i]; }
    float inv = 1.f / s;
#pragma unroll
    for (int i = 0; i < 12; i++) p[i] = e[i] * inv;
}

// ---------- deformable sampling: lane = channel (32/item), 8 items/block ----------
__global__ __launch_bounds__(256) void k_msda(const u16* __restrict__ value, const float* __restrict__ offaw,
                                              const float* __restrict__ ref, float* __restrict__ samp)
{
    int it = blockIdx.x * 8 + (threadIdx.x >> 5);
    int d  = threadIdx.x & 31;
    int h = it & 7, row = it >> 3;
    int b = row / 300;
    const float* rf = ref + (size_t)row * 4;
    float rx = rf[0], ry = rf[1];
    float rw = rf[2] * 0.125f, rh = rf[3] * 0.125f;   // /P * 0.5
    const float* offp = offaw + (size_t)row * 288 + h * 24;
    const float* awp  = offaw + (size_t)row * 288 + 192 + h * 12;
    const u16* vb = value + ((size_t)(b * 8 + h)) * 8400 * 32 + d;
    const int HW[3] = {80, 40, 20};
    const int st[3] = {0, 6400, 8000};
    float acc = 0.f;
#pragma unroll
    for (int lv = 0; lv < 3; lv++) {
        int Wl = HW[lv], Hl = HW[lv];
        float Wf = (float)Wl, Hf = (float)Hl;
#pragma unroll
        for (int p = 0; p < 4; p++) {
            float a = awp[lv * 4 + p];
            float x = (rx + offp[lv*8 + p*2]     * rw) * Wf - 0.5f;
            float y = (ry + offp[lv*8 + p*2 + 1] * rh) * Hf - 0.5f;
            float xf = floorf(x), yf = floorf(y);
            float wx = x - xf, wy = y - yf;
            int x0 = (int)xf, y0 = (int)yf;
#pragma unroll
            for (int t = 0; t < 4; t++) {
                int xx = x0 + (t & 1), yy = y0 + (t >> 1);
                if (xx >= 0 && xx < Wl && yy >= 0 && yy < Hl) {
                    float w = ((t & 1) ? wx : 1.f - wx) * ((t >> 1) ? wy : 1.f - wy);
                    acc += a * w * bf2f(vb[(size_t)(st[lv] + yy * Wl + xx) * 32]);
                }
            }
        }
    }
    samp[(size_t)row * 256 + h * 32 + d] = acc;
}

// ---------- qpe hidden: relu(ref(4) @ W1(4,512) + b1) ----------
__global__ void k_qpe_hidden(const float* __restrict__ ref, const float* __restrict__ W1,
                             const float* __restrict__ b1, float* __restrict__ hid)
{
    int idx = blockIdx.x * 256 + threadIdx.x;
    if (idx >= 4800 * 512) return;
    int row = idx >> 9, col = idx & 511;
    const float* r = ref + (size_t)row * 4;
    float v = b1[col] + r[0]*W1[col] + r[1]*W1[512+col] + r[2]*W1[1024+col] + r[3]*W1[1536+col];
    hid[idx] = fmaxf(v, 0.f);
}

// ---------- bbox tail ----------
__global__ __launch_bounds__(64) void k_bb3(const float* __restrict__ bb2, const float* __restrict__ W3,
                                            const float* __restrict__ b3, float* __restrict__ ref)
{
    int row = blockIdx.x;
    int lane = threadIdx.x;
    const float* xr = bb2 + (size_t)row * 256;
    float s0 = 0, s1 = 0, s2 = 0, s3 = 0;
#pragma unroll
    for (int k = lane; k < 256; k += 64) {
        float xv = xr[k];
        float4 w = *(const float4*)(W3 + k * 4);
        s0 += xv * w.x; s1 += xv * w.y; s2 += xv * w.z; s3 += xv * w.w;
    }
#pragma unroll
    for (int off = 32; off >= 1; off >>= 1) {
        s0 += __shfl_xor(s0, off); s1 += __shfl_xor(s1, off);
        s2 += __shfl_xor(s2, off); s3 += __shfl_xor(s3, off);
    }
    if (lane == 0) {
        float sv[4] = {s0, s1, s2, s3};
        float* rr = ref + (size_t)row * 4;
#pragma unroll
        for (int j = 0; j < 4; j++) {
            float v = sv[j] + b3[j];
            float o = rr[j];
            o = fminf(fmaxf(o, 1e-5f), 1.f - 1e-5f);
            float inv = logf(o / (1.f - o));
            rr[j] = 1.f / (1.f + expf(-(v + inv)));
        }
    }
}

// ---------- small utility kernels ----------
__global__ void k_cvt_bf16(const float* __restrict__ in, u16* __restrict__ out, int n4)
{
    int i = blockIdx.x * 256 + threadIdx.x;
    if (i >= n4) return;
    float4 v = ((const float4*)in)[i];
    ushort4 h; h.x = f2bf(v.x); h.y = f2bf(v.y); h.z = f2bf(v.z); h.w = f2bf(v.w);
    ((ushort4*)out)[i] = h;
}
__global__ void k_copy4(const float* __restrict__ in, float* __restrict__ out, int n4)
{
    int i = blockIdx.x * 256 + threadIdx.x;
    if (i >= n4) return;
    ((float4*)out)[i] = ((const float4*)in)[i];
}
__global__ void k_sigmoid(const float* __restrict__ in, float* __restrict__ out, int n)
{
    int i = blockIdx.x * 256 + threadIdx.x;
    if (i >= n) return;
    out[i] = 1.f / (1.f + __expf(-in[i]));
}

// ---------- host-side launch helpers ----------
static inline dim3 g32(int M, int N) { return dim3((M + 31) / 32, (N + 127) / 128); }

static void gemm_plain(const float* A, const u16* Bt, const float* bias, float* C,
                       int M, int N, int K, hipStream_t s) {
    k_gemm<32, 0, 0, false, false><<<g32(M, N), 256, 0, s>>>((const void*)A, nullptr, Bt, bias, nullptr, (void*)C, M, N, K);
}
static void gemm_add(const float* A, const float* A2, const u16* Bt, const float* bias, float* C,
                     int M, int N, int K, hipStream_t s) {
    k_gemm<32, 1, 0, false, false><<<g32(M, N), 256, 0, s>>>((const void*)A, A2, Bt, bias, nullptr, (void*)C, M, N, K);
}
static void gemm_resid(const float* A, const u16* Bt, const float* bias, const float* resid, float* C,
                       int M, int N, int K, hipStream_t s) {
    k_gemm<32, 0, 0, false, true><<<g32(M, N), 256, 0, s>>>((const void*)A, nullptr, Bt, bias, resid, (void*)C, M, N, K);
}
static void gemm_relu(const float* A, const u16* Bt, const float* bias, float* C,
                      int M, int N, int K, hipStream_t s) {
    k_gemm<32, 0, 0, true, false><<<g32(M, N), 256, 0, s>>>((const void*)A, nullptr, Bt, bias, nullptr, (void*)C, M, N, K);
}
static void gemm_value(const u16* A, const u16* Bt, const float* bias, u16* C, hipStream_t s) {
    k_gemm<64, 2, 1, false, false><<<dim3(2100, 2), 256, 0, s>>>((const void*)A, nullptr, Bt, bias, nullptr, (void*)C, 134400, 256, 256);
}

extern "C" void kernel_launch(void* const* d_in, const int* in_sizes, int n_in,
                              void* d_out, int out_size, void* d_ws, size_t ws_size,
                              hipStream_t stream)
{
    const float* tgt       = (const float*)d_in[0];
    const float* ref_unact = (const float*)d_in[1];
    const float* memory    = (const float*)d_in[2];
    const float* self_Wq = (const float*)d_in[4];
    const float* self_bq = (const float*)d_in[5];
    const float* self_Wk = (const float*)d_in[6];
    const float* self_bk = (const float*)d_in[7];
    const float* self_Wv = (const float*)d_in[8];
    const float* self_bv = (const float*)d_in[9];
    const float* self_Wo = (const float*)d_in[10];
    const float* self_bo = (const float*)d_in[11];
    const float* ln1_g = (const float*)d_in[12];
    const float* ln1_b = (const float*)d_in[13];
    const float* ln2_g = (const float*)d_in[14];
    const float* ln2_b = (const float*)d_in[15];
    const float* ln3_g = (const float*)d_in[16];
    const float* ln3_b = (const float*)d_in[17];
    const float* off_W = (const float*)d_in[18];
    const float* off_b = (const float*)d_in[19];
    const float* aw_W  = (const float*)d_in[20];
    const float* aw_b  = (const float*)d_in[21];
    const float* val_W = (const float*)d_in[22];
    const float* val_b = (const float*)d_in[23];
    const float* out_W = (const float*)d_in[24];
    const float* out_b = (const float*)d_in[25];
    const float* ffn_W1 = (const float*)d_in[26];
    const float* ffn_b1 = (const float*)d_in[27];
    const float* ffn_W2 = (const float*)d_in[28];
    const float* ffn_b2 = (const float*)d_in[29];
    const float* qph_W1 = (const float*)d_in[30];
    const float* qph_b1 = (const float*)d_in[31];
    const float* qph_W2 = (const float*)d_in[32];
    const float* qph_b2 = (const float*)d_in[33];
    const float* bb_W1 = (const float*)d_in[34];
    const float* bb_b1 = (const float*)d_in[35];
    const float* bb_W2 = (const float*)d_in[36];
    const float* bb_b2 = (const float*)d_in[37];
    const float* bb_W3 = (const float*)d_in[38];
    const float* bb_b3 = (const float*)d_in[39];
    const float* sc_W  = (const float*)d_in[40];
    const float* sc_b  = (const float*)d_in[41];
    float* out_f = (float*)d_out;

    // ---- workspace layout (bytes) ----
    char* w = (char*)d_ws;
    u16* mem_bf = (u16*)(w + 0);                // 68,812,800 B
    u16* value  = (u16*)(w + 68812800);         // 68,812,800 B
    const size_t F0 = 137625600;
    float* ws_out   = (float*)(w + F0);
    float* ws_tmp   = (float*)(w + F0 +  4915200);
    float* ws_qpe   = (float*)(w + F0 +  9830400);
    float* ws_hid   = (float*)(w + F0 + 14745600);  // 4800x512
    float* ws_qk    = (float*)(w + F0 + 24576000);  // 4800x512 (Q | K)
    float* ws_v     = (float*)(w + F0 + 34406400);
    float* ws_attn  = (float*)(w + F0 + 39321600);
    float* ws_offaw = (float*)(w + F0 + 44236800);  // 4800x288 (off | aw)
    float* ws_samp  = (float*)(w + F0 + 49766400);
    float* ws_ffn   = (float*)(w + F0 + 54681600);  // 4800x1024
    float* ws_bb1   = (float*)(w + F0 + 74342400);
    float* ws_bb2   = (float*)(w + F0 + 79257600);
    float* ws_ref   = (float*)(w + F0 + 84172800);  // 4800x4
    float* bias_qk  = (float*)(w + F0 + 84256800);  // 6 x 512
    float* bias_oa  = (float*)(w + F0 + 84269088);  // 6 x 288
    // ---- bf16 transposed weights (u16 elements), 16B-aligned ----
    u16* wt = (u16*)(w + F0 + 84276000);
    u16* wt_qk    = wt;                    // 6 x 512x256
    u16* wt_v     = wt_qk    + 786432;     // 6 x 65536
    u16* wt_o     = wt_v     + 393216;
    u16* wt_offaw = wt_o     + 393216;     // 6 x 288x256
    u16* wt_val   = wt_offaw + 442368;
    u16* wt_out   = wt_val   + 393216;
    u16* wt_f1    = wt_out   + 393216;     // 6 x 262144
    u16* wt_f2    = wt_f1    + 1572864;
    u16* wt_b1    = wt_f2    + 1572864;
    u16* wt_b2    = wt_b1    + 393216;
    u16* wt_qp2   = wt_b2    + 393216;     // 131072
    u16* wt_sc    = wt_qp2   + 131072;     // 20480

    // ---- init: weight transposes + bias packs ----
    k_wt<<<dim3(8, 8, 6),  256, 0, stream>>>(self_Wq, wt_qk,            256, 256, 131072);
    k_wt<<<dim3(8, 8, 6),  256, 0, stream>>>(self_Wk, wt_qk + 65536,    256, 256, 131072);
    k_wt<<<dim3(8, 8, 6),  256, 0, stream>>>(self_Wv, wt_v,             256, 256, 65536);
    k_wt<<<dim3(8, 8, 6),  256, 0, stream>>>(self_Wo, wt_o,             256, 256, 65536);
    k_wt<<<dim3(8, 6, 6),  256, 0, stream>>>(off_W,   wt_offaw,         256, 192, 73728);
    k_wt<<<dim3(8, 3, 6),  256, 0, stream>>>(aw_W,    wt_offaw + 49152, 256, 96,  73728);
    k_wt<<<dim3(8, 8, 6),  256, 0, stream>>>(val_W,   wt_val,           256, 256, 65536);
    k_wt<<<dim3(8, 8, 6),  256, 0, stream>>>(out_W,   wt_out,           256, 256, 65536);
    k_wt<<<dim3(8, 32, 6), 256, 0, stream>>>(ffn_W1,  wt_f1,            256, 1024, 262144);
    k_wt<<<dim3(32, 8, 6), 256, 0, stream>>>(ffn_W2,  wt_f2,            1024, 256, 262144);
    k_wt<<<dim3(8, 8, 6),  256, 0, stream>>>(bb_W1,   wt_b1,            256, 256, 65536);
    k_wt<<<dim3(8, 8, 6),  256, 0, stream>>>(bb_W2,   wt_b2,            256, 256, 65536);
    k_wt<<<dim3(16, 8, 1), 256, 0, stream>>>(qph_W2,  wt_qp2,           512, 256, 131072);
    k_wt<<<dim3(8, 3, 1),  256, 0, stream>>>(sc_W + (size_t)5 * 20480, wt_sc, 256, 80, 20480);
    k_packbias<<<dim3(1, 1, 6), 256, 0, stream>>>(self_bq, self_bk, 256, 256, bias_qk);
    k_packbias<<<dim3(1, 1, 6), 256, 0, stream>>>(off_b, aw_b, 192, 96, bias_oa);

    k_cvt_bf16<<<33600, 256, 0, stream>>>(memory, mem_bf, 8601600);
    k_copy4   <<<1200,  256, 0, stream>>>(tgt, ws_out, 307200);
    k_sigmoid <<<75,    256, 0, stream>>>(ref_unact, ws_ref, 19200);

    for (int l = 0; l < 6; l++) {
        // qpe = relu(ref @ qph_W1 + b1) @ qph_W2 + b2
        k_qpe_hidden<<<9600, 256, 0, stream>>>(ws_ref, qph_W1, qph_b1, ws_hid);
        gemm_plain(ws_hid, wt_qp2, qph_b2, ws_qpe, 4800, 256, 512, stream);

        // self-attention (fused Q|K projection, MFMA flash MHA)
        gemm_add(ws_out, ws_qpe, wt_qk + (size_t)l * 131072, bias_qk + l * 512, ws_qk, 4800, 512, 256, stream);
        gemm_plain(ws_out, wt_v + (size_t)l * 65536, self_bv + l * 256, ws_v, 4800, 256, 256, stream);
        k_mha3<<<dim3(5, 128), 256, 0, stream>>>(ws_qk, ws_v, ws_attn);
        gemm_resid(ws_attn, wt_o + (size_t)l * 65536, self_bo + l * 256, ws_out, ws_tmp, 4800, 256, 256, stream);
        k_ln<<<1200, 256, 0, stream>>>(ws_tmp, ln1_g + l * 256, ln1_b + l * 256, ws_out, 4800);

        // value projection (bf16 A, bf16 out, (b,h,pix,hd) layout)
        gemm_value(mem_bf, wt_val + (size_t)l * 65536, val_b + l * 256, value, stream);

        // deformable attention (fused off|aw projection)
        gemm_add(ws_out, ws_qpe, wt_offaw + (size_t)l * 73728, bias_oa + l * 288, ws_offaw, 4800, 288, 256, stream);
        k_awsm<<<150, 256, 0, stream>>>(ws_offaw, 38400);
        k_msda<<<4800, 256, 0, stream>>>(value, ws_offaw, ws_ref, ws_samp);
        gemm_resid(ws_samp, wt_out + (size_t)l * 65536, out_b + l * 256, ws_out, ws_tmp, 4800, 256, 256, stream);
        k_ln<<<1200, 256, 0, stream>>>(ws_tmp, ln2_g + l * 256, ln2_b + l * 256, ws_out, 4800);

        // FFN
        gemm_relu(ws_out, wt_f1 + (size_t)l * 262144, ffn_b1 + l * 1024, ws_ffn, 4800, 1024, 256, stream);
        gemm_resid(ws_ffn, wt_f2 + (size_t)l * 262144, ffn_b2 + l * 256, ws_out, ws_tmp, 4800, 256, 1024, stream);
        k_ln<<<1200, 256, 0, stream>>>(ws_tmp, ln3_g + l * 256, ln3_b + l * 256, ws_out, 4800);

        // bbox head + ref update
        gemm_relu(ws_out, wt_b1 + (size_t)l * 65536, bb_b1 + l * 256, ws_bb1, 4800, 256, 256, stream);
        gemm_relu(ws_bb1, wt_b2 + (size_t)l * 65536, bb_b2 + l * 256, ws_bb2, 4800, 256, 256, stream);
        k_bb3<<<4800, 64, 0, stream>>>(ws_bb2, bb_W3 + (size_t)l * 1024, bb_b3 + l * 4, ws_ref);
    }

    // outputs: ref (19200 f32) then logits (4800x80 f32)
    k_copy4<<<19, 256, 0, stream>>>(ws_ref, out_f, 4800);
    gemm_plain(ws_out, wt_sc, sc_b + 5 * 80, out_f + 19200, 4800, 80, 256, stream);
}